// Round 7
// baseline (479.793 us; speedup 1.0000x reference)
//
#include <hip/hip_runtime.h>
#include <hip/hip_bf16.h>

#define NU 40000
#define ND 20000
#define NUP 40064   // 313*128
#define NDP 20096   // 157*128
#define HIDC 256
#define NHEAD 4
#define NEDGE 80000
#define CHUNK 2048
#define NCH 20      // ceil(NU/CHUNK)

typedef __attribute__((ext_vector_type(8))) short bf16x8;
typedef __attribute__((ext_vector_type(8))) unsigned short u16x8;
typedef __attribute__((ext_vector_type(4))) float f32x4;

static __device__ __forceinline__ float b2f(unsigned short u) {
  union { unsigned int u; float f; } x; x.u = (unsigned int)u << 16; return x.f;
}
static __device__ __forceinline__ unsigned short f2b(float f) {
  union { float f; unsigned int u; } x; x.f = f;
  unsigned int r = x.u + 0x7FFFu + ((x.u >> 16) & 1u);
  return (unsigned short)(r >> 16);
}

static __device__ __forceinline__ void gload_lds16(const void* g, void* l) {
  __builtin_amdgcn_global_load_lds((const __attribute__((address_space(1))) unsigned int*)g,
                                   (__attribute__((address_space(3))) unsigned int*)l, 16, 0, 0);
}

// ============ bf16 MFMA GEMM: C = act(A @ Bt^T + bias) ============
// A: [Mpad][K] bf16. Bt: [Npad][K] bf16. 1D grid = ceil(Mblk/8)*8*Nx, 256 thr.
// XCD-colocating swizzle: all Nx col-blocks of a row-panel share id mod 8.
// ACT 0: none, 1: relu, 2: tanh+colsum->atomicAdd(Cf[col]),
// ACT 3: skip-mix epilogue: Cb = f2b(su*(acc+bias) + (1-su)*b2f(xprev)) (bf16)
template<int ACT>
__global__ __launch_bounds__(256)
void gemm_bf16(const unsigned short* __restrict__ A,
               const unsigned short* __restrict__ Bt,
               const float* __restrict__ bias,
               float* __restrict__ Cf, int ldcf,
               unsigned short* __restrict__ Cb, int ldcb,
               int M, int N, int K, int Mblk,
               const float* __restrict__ skipp,
               const unsigned short* __restrict__ xprev)
{
  __shared__ __attribute__((aligned(128))) unsigned char smem[32768];
  unsigned short* ldsA = (unsigned short*)smem;
  unsigned short* ldsB = ldsA + 8192;
  float* ldsE = (float*)smem;   // epilogue overlay: 32 rows x (9/8-padded 128 cols) = 18.9KB

  const int Nx = (N + 127) >> 7;
  const int S = Nx << 3;
  const int flat = blockIdx.x;
  const int jj = flat % S, kq = flat / S;
  const int bx = jj >> 3, by = (kq << 3) + (jj & 7);
  if (by >= Mblk) return;

  const int tid  = threadIdx.x;
  const int lane = tid & 63, wv = tid >> 6;
  const int row0 = by * 128, col0 = bx * 128;

  const int rS = wv * 32 + (lane >> 3);
  const int sS = (lane & 7) ^ (lane >> 3);

  const int lr = lane & 15, lk = lane >> 4;
  const int wr = wv >> 1, wc = wv & 1;
  const int swz = lr & 7;

  f32x4 acc[4][4] = {};

  for (int k0 = 0; k0 < K; k0 += 64) {
#pragma unroll
    for (int i = 0; i < 4; i++) {
      size_t ga = (size_t)(row0 + rS + i * 8) * K + k0 + sS * 8;
      gload_lds16(A + ga, ldsA + wv * 2048 + i * 512);
      size_t gb = (size_t)(col0 + rS + i * 8) * K + k0 + sS * 8;
      gload_lds16(Bt + gb, ldsB + wv * 2048 + i * 512);
    }
    __syncthreads();
#pragma unroll
    for (int half = 0; half < 2; half++) {
      const int k8 = half * 4 + lk;
      const int so = (k8 ^ swz) << 3;
      bf16x8 av[4], bv[4];
#pragma unroll
      for (int m = 0; m < 4; m++)
        av[m] = *(const bf16x8*)&ldsA[(wr * 64 + m * 16 + lr) * 64 + so];
#pragma unroll
      for (int n = 0; n < 4; n++)
        bv[n] = *(const bf16x8*)&ldsB[(wc * 64 + n * 16 + lr) * 64 + so];
#pragma unroll
      for (int m = 0; m < 4; m++)
#pragma unroll
        for (int n = 0; n < 4; n++)
          acc[m][n] = __builtin_amdgcn_mfma_f32_16x16x32_bf16(av[m], bv[n], acc[m][n], 0, 0, 0);
    }
    __syncthreads();
  }

  if (ACT == 2) {
    __shared__ float csum[64];
    if (tid < 64) csum[tid] = 0.f;
    __syncthreads();
#pragma unroll
    for (int n = 0; n < 4; n++) {
      int col = col0 + wc * 64 + n * 16 + lr;
      if (col < N) {
        float bi = bias[col];
        float local = 0.f;
#pragma unroll
        for (int m = 0; m < 4; m++)
#pragma unroll
          for (int g = 0; g < 4; g++) {
            int row = row0 + wr * 64 + m * 16 + lk * 4 + g;
            if (row < M) local += tanhf(acc[m][n][g] + bi);
          }
        atomicAdd(&csum[col], local);
      }
    }
    __syncthreads();
    if (tid < 64) atomicAdd(&Cf[tid], csum[tid]);
    return;
  }

  // ===== LDS-staged epilogue: four 32-row chunks, 9/8-padded layout =====
  // word (lrow, col) -> lrow*148 + 9*(col>>3) + (col&7)
  // write: 2 lanes/bank (free); read: ~2-way avg. LDS use: 18.9KB (overlays staging).
  float su = 0.f;
  if (ACT == 3) su = 1.f / (1.f + expf(-skipp[0]));
  float bi[4];
#pragma unroll
  for (int n = 0; n < 4; n++) {
    int col = col0 + wc * 64 + n * 16 + lr;
    bi[n] = (col < N) ? bias[col] : 0.f;
  }

#pragma unroll
  for (int ch = 0; ch < 4; ch++) {
    __syncthreads();
    if (wr == (ch >> 1)) {
#pragma unroll
      for (int mm = 0; mm < 2; mm++) {
        int m = 2 * (ch & 1) + mm;
#pragma unroll
        for (int n = 0; n < 4; n++) {
          int col = wc * 64 + n * 16 + lr;
#pragma unroll
          for (int g = 0; g < 4; g++) {
            int lrow = mm * 16 + lk * 4 + g;
            int row = row0 + ch * 32 + lrow;
            float v = acc[m][n][g] + bi[n];
            if (ACT == 1) v = fmaxf(v, 0.f);
            if (ACT == 3 && row < M)
              v = su * v + (1.f - su) * b2f(xprev[(size_t)row * 256 + col0 + col]);
            if (row >= M) v = 0.f;
            ldsE[lrow * 148 + 9 * (col >> 3) + (col & 7)] = v;
          }
        }
      }
    }
    __syncthreads();
#pragma unroll
    for (int i = 0; i < 2; i++) {
      int c = tid + i * 256;            // 0..511 over 32 rows x 16 col-chunks
      int lrow = c >> 4, cc = c & 15;
      int row = row0 + ch * 32 + lrow;
      int colb = cc * 8;
      float v[8];
#pragma unroll
      for (int q = 0; q < 8; q++) v[q] = ldsE[lrow * 148 + 9 * cc + q];
      if (Cb) {
        u16x8 o;
#pragma unroll
        for (int q = 0; q < 8; q++) o[q] = f2b(v[q]);
        *(u16x8*)(Cb + (size_t)row * ldcb + col0 + colb) = o;
      }
      if (Cf && row < M) {
        int col = col0 + colb;
        if (col < N)
          *(float4*)&Cf[(size_t)row * ldcf + col] = make_float4(v[0], v[1], v[2], v[3]);
        if (col + 4 < N)
          *(float4*)&Cf[(size_t)row * ldcf + col + 4] = make_float4(v[4], v[5], v[6], v[7]);
      }
    }
  }
}

// ============ prep kernels ============
__global__ void conv_pad(const float* __restrict__ in, unsigned short* __restrict__ out,
                         int M, int C, int total)
{
  int t = blockIdx.x * 256 + threadIdx.x;
  if (t >= total) return;
  int r = t / C;
  out[t] = (r < M) ? f2b(in[t]) : 0;
}

__global__ void transp_conv(const float* __restrict__ W, int ldw, int coloff,
                            unsigned short* __restrict__ Bt, int K, int N, int total)
{
  int t = blockIdx.x * 256 + threadIdx.x;
  if (t >= total) return;
  int n = t / K, k = t - n * K;
  Bt[t] = (n < N) ? f2b(W[(size_t)k * ldw + coloff + n]) : 0;
}

__global__ void comb_w_t(const float* __restrict__ Wkqv, int coloff,
                         const float* __restrict__ Wh, unsigned short* __restrict__ Bt)
{
  int t = blockIdx.x * 256 + threadIdx.x;  // n*256 + c
  int n = t >> 8, c = t & 255;
  int hh = n >> 6, e = n & 63;
  float acc = 0.f;
  for (int d = 0; d < 64; d++)
    acc += Wkqv[(size_t)c * 768 + coloff + hh * 64 + d] * Wh[hh * 4096 + d * 64 + e];
  Bt[t] = f2b(acc);
}

__global__ void comb_b(const float* __restrict__ bkqv, int coloff,
                       const float* __restrict__ Wh, float* __restrict__ bout)
{
  int j = threadIdx.x;
  int hh = j >> 6, e = j & 63;
  float acc = 0.f;
  for (int d = 0; d < 64; d++)
    acc += bkqv[coloff + hh * 64 + d] * Wh[hh * 4096 + d * 64 + e];
  bout[j] = acc;
}

__global__ void copy_f32(const float* __restrict__ src, float* __restrict__ dst, int n)
{
  int t = blockIdx.x * 256 + threadIdx.x;
  if (t < n) dst[t] = src[t];
}

// ============ CSR build ============
__global__ void hist_dst(const int* __restrict__ ei, int ne, int* __restrict__ cnt)
{
  int t = blockIdx.x * 256 + threadIdx.x;
  if (t < ne) atomicAdd(&cnt[ei[ne + t]], 1);
}

__global__ __launch_bounds__(256)
void scan_partial(const int* __restrict__ cnt, int* __restrict__ csums)
{
  int b = blockIdx.x;
  int rel = b / NCH, ch = b - rel * NCH;
  const int* c = cnt + (size_t)rel * NU;
  int t = threadIdx.x;
  int i0 = ch * CHUNK + t * 8;
  int s = 0;
#pragma unroll
  for (int j = 0; j < 8; j++) { int i = i0 + j; if (i < NU) s += c[i]; }
  __shared__ int ps[256];
  ps[t] = s;
  __syncthreads();
  for (int d = 128; d > 0; d >>= 1) { if (t < d) ps[t] += ps[t + d]; __syncthreads(); }
  if (t == 0) csums[b] = ps[0];
}

__global__ void scan_mid(const int* __restrict__ csums, int* __restrict__ coffs,
                         int* __restrict__ rs)
{
  int r = threadIdx.x;
  if (r >= 3) return;
  int run = 0;
  for (int ch = 0; ch < NCH; ch++) { coffs[r * NCH + ch] = run; run += csums[r * NCH + ch]; }
  rs[(size_t)r * NUP + NU] = run;
}

__global__ __launch_bounds__(256)
void scan_final(const int* __restrict__ cnt, const int* __restrict__ coffs,
                int* __restrict__ rs)
{
  int b = blockIdx.x;
  int rel = b / NCH, ch = b - rel * NCH;
  const int* c = cnt + (size_t)rel * NU;
  int* r = rs + (size_t)rel * NUP;
  int t = threadIdx.x;
  int i0 = ch * CHUNK + t * 8;
  int loc[8]; int s = 0;
#pragma unroll
  for (int j = 0; j < 8; j++) { int i = i0 + j; loc[j] = (i < NU) ? c[i] : 0; s += loc[j]; }
  __shared__ int ps[256];
  ps[t] = s;
  __syncthreads();
  for (int d = 1; d < 256; d <<= 1) {
    int o = (t >= d) ? ps[t - d] : 0;
    __syncthreads();
    ps[t] += o;
    __syncthreads();
  }
  int run = coffs[b] + ps[t] - s;
#pragma unroll
  for (int j = 0; j < 8; j++) { int i = i0 + j; if (i < NU) { r[i] = run; run += loc[j]; } }
}

// ============ HAN ============
__global__ void han_alsd(const float* __restrict__ h,
                         const float* __restrict__ a_s1, const float* __restrict__ a_d1,
                         const float* __restrict__ a_s2, const float* __restrict__ a_d2,
                         float* __restrict__ als1, float* __restrict__ ald1,
                         float* __restrict__ als2, float* __restrict__ ald2)
{
  int t = blockIdx.x * 256 + threadIdx.x;
  if (t >= NU * NHEAD) return;
  int n = t >> 2, hh = t & 3;
  const float* hp = h + (size_t)n * 64 + hh * 16;
  float s1 = 0, d1 = 0, s2 = 0, d2 = 0;
#pragma unroll
  for (int d = 0; d < 16; d++) {
    float v = hp[d];
    s1 += v * a_s1[hh * 16 + d]; d1 += v * a_d1[hh * 16 + d];
    s2 += v * a_s2[hh * 16 + d]; d2 += v * a_d2[hh * 16 + d];
  }
  als1[t] = s1; ald1[t] = d1; als2[t] = s2; ald2[t] = d2;
}

__global__ void han_fill(const int* __restrict__ ei, int ne,
                         const float* __restrict__ als, const float* __restrict__ ald,
                         const int* __restrict__ rs, int* __restrict__ cur,
                         int* __restrict__ esrc, float* __restrict__ aev)
{
  int t = blockIdx.x * 256 + threadIdx.x;
  if (t >= ne * 4) return;
  int e = t >> 2, hh = t & 3;
  int s = ei[e], d = ei[ne + e];
  float al = als[s * 4 + hh] + ald[d * 4 + hh];
  al = (al >= 0.f) ? al : 0.2f * al;
  float ex = expf(al);
  int pos = 0;
  if (hh == 0) pos = rs[d] + atomicAdd(&cur[d], 1);
  pos = __shfl(pos, 0, 4);
  aev[pos * 4 + hh] = ex;
  if (hh == 0) esrc[pos] = s;
}

__global__ __launch_bounds__(256)
void han_gather(const int* __restrict__ rs, const int* __restrict__ esrc,
                const float* __restrict__ aev, const float* __restrict__ h,
                unsigned short* __restrict__ obf)
{
  int gid = blockIdx.x * 256 + threadIdx.x;
  int wid = gid >> 6, lane = gid & 63;
  if (wid >= NUP) return;
  int head = lane >> 4;
  int beg = 0, end = 0;
  if (wid < NU) { beg = rs[wid]; end = rs[wid + 1]; }
  float asum = 0.f;
  for (int i = beg; i < end; i++) asum += aev[i * 4 + head];
  float inv = 1.f / (asum + 1e-16f);
  float a = 0.f;
  for (int i = beg; i < end; i++)
    a += aev[i * 4 + head] * inv * h[(size_t)esrc[i] * 64 + lane];
  obf[(size_t)wid * 64 + lane] = f2b(fmaxf(a, 0.f));
}

__global__ void sem_final2(const float* __restrict__ colpart2,
                           const float* __restrict__ q_sem, float* __restrict__ semv)
{
  int t = threadIdx.x;            // 128
  int j = t & 63;
  __shared__ float sv[128];
  sv[t] = colpart2[t] * q_sem[j] * (1.0f / NU);
  __syncthreads();
  if (t == 0) {
    float s0 = 0, s1 = 0;
    for (int i = 0; i < 64; i++) { s0 += sv[i]; s1 += sv[64 + i]; }
    float m = fmaxf(s0, s1);
    float e0 = expf(s0 - m), e1 = expf(s1 - m);
    semv[0] = e0 / (e0 + e1); semv[1] = e1 / (e0 + e1);
  }
}

// ============ HGT ============
__global__ void hgt_fill(const int* __restrict__ ei, int ne,
                         const unsigned short* __restrict__ qb,
                         const unsigned short* __restrict__ kb, int ks, int voff,
                         const float* __restrict__ p,
                         const int* __restrict__ rs, int* __restrict__ cur,
                         int* __restrict__ esrc, float* __restrict__ aev)
{
  int t = blockIdx.x * 256 + threadIdx.x;
  if (t >= ne * 4) return;
  int e = t >> 2, hh = t & 3;
  int s = ei[e], d = ei[ne + e];
  const uint4* qv = (const uint4*)(qb + (size_t)d * 768 + 256 + hh * 64);
  const uint4* kv = (const uint4*)(kb + (size_t)s * ks + hh * 64);
  float acc = 0.f;
#pragma unroll
  for (int i = 0; i < 8; i++) {
    uint4 a = qv[i], b = kv[i];
    unsigned int aw[4] = {a.x, a.y, a.z, a.w};
    unsigned int bw[4] = {b.x, b.y, b.z, b.w};
#pragma unroll
    for (int u = 0; u < 4; u++) {
      acc += b2f((unsigned short)(aw[u] & 0xffff)) * b2f((unsigned short)(bw[u] & 0xffff));
      acc += b2f((unsigned short)(aw[u] >> 16))    * b2f((unsigned short)(bw[u] >> 16));
    }
  }
  float ex = expf(acc * p[hh] * 0.125f);
  int pos = 0;
  if (hh == 0) pos = rs[d] + atomicAdd(&cur[d], 1);
  pos = __shfl(pos, 0, 4);
  aev[pos * 4 + hh] = ex;
  if (hh == 0) esrc[pos] = voff + s * ks;
}

__global__ __launch_bounds__(256)
void hgt_gather(const int* __restrict__ rs, const int* __restrict__ esrc,
                const float* __restrict__ aev, const unsigned short* __restrict__ vbase,
                unsigned short* __restrict__ houtb)
{
  int gid = blockIdx.x * 256 + threadIdx.x;
  int wid = gid >> 6, lane = gid & 63;
  if (wid >= NUP) return;
  int head = lane >> 4;
  int beg = 0, end = 0;
  if (wid < NU) { beg = rs[wid]; end = rs[wid + 1]; }
  float asum = 0.f;
  for (int i = beg; i < end; i++) asum += aev[i * 4 + head];
  float inv = 1.f / (asum + 1e-16f);
  float a0 = 0, a1 = 0, a2 = 0, a3 = 0;
  for (int i = beg; i < end; i++) {
    float w = aev[i * 4 + head] * inv;
    const ushort4 v = *(const ushort4*)(vbase + (size_t)esrc[i] + lane * 4);
    a0 += b2f(v.x) * w; a1 += b2f(v.y) * w; a2 += b2f(v.z) * w; a3 += b2f(v.w) * w;
  }
  ushort4 o;
  o.x = f2b(0.5f * a0 * (1.f + erff(a0 * 0.70710678118654752f)));
  o.y = f2b(0.5f * a1 * (1.f + erff(a1 * 0.70710678118654752f)));
  o.z = f2b(0.5f * a2 * (1.f + erff(a2 * 0.70710678118654752f)));
  o.w = f2b(0.5f * a3 * (1.f + erff(a3 * 0.70710678118654752f)));
  *(ushort4*)(houtb + (size_t)wid * 256 + lane * 4) = o;
}

// ============ epilogues ============
__global__ void fill_ref_b(const unsigned short* __restrict__ obf1,
                           const unsigned short* __restrict__ obf2,
                           const float* __restrict__ semv, unsigned short* __restrict__ afinb)
{
  int t = blockIdx.x * 256 + threadIdx.x;  // n*64 + j
  if (t >= NU * 64) return;
  int n = t >> 6, j = t & 63;
  float v = semv[0] * b2f(obf1[t]) + semv[1] * b2f(obf2[t]);  // already relu'd
  afinb[(size_t)n * 320 + 256 + j] = f2b(v);
}

// ------------------------------------------------------------------
extern "C" void kernel_launch(void* const* d_in, const int* in_sizes, int n_in,
                              void* d_out, int out_size, void* d_ws, size_t ws_size,
                              hipStream_t stream)
{
  (void)in_sizes; (void)n_in; (void)out_size; (void)ws_size;
  const float* x_user     = (const float*)d_in[0];
  const float* x_drug     = (const float*)d_in[1];
  const float* x_user_ref = (const float*)d_in[2];
  const int*   ei_du      = (const int*)d_in[4];
  const int*   ei_uu      = (const int*)d_in[5];
  const int*   ei_r1      = (const int*)d_in[6];
  const int*   ei_r2      = (const int*)d_in[7];
  const float* W_han      = (const float*)d_in[8];
  const float* b_han      = (const float*)d_in[9];
  const float* a_src_r1   = (const float*)d_in[10];
  const float* a_dst_r1   = (const float*)d_in[11];
  const float* a_src_r2   = (const float*)d_in[12];
  const float* a_dst_r2   = (const float*)d_in[13];
  const float* Wk_sem     = (const float*)d_in[14];
  const float* bk_sem     = (const float*)d_in[15];
  const float* q_sem      = (const float*)d_in[16];
  const float* W_in_user  = (const float*)d_in[17];
  const float* b_in_user  = (const float*)d_in[18];
  const float* W_in_drug  = (const float*)d_in[19];
  const float* b_in_drug  = (const float*)d_in[20];
  const float* W_kqv_user = (const float*)d_in[21];
  const float* b_kqv_user = (const float*)d_in[22];
  const float* W_kqv_drug = (const float*)d_in[23];
  const float* b_kqv_drug = (const float*)d_in[24];
  const float* Wk_du      = (const float*)d_in[28];
  const float* Wv_du      = (const float*)d_in[29];
  const float* p_du       = (const float*)d_in[30];
  const float* Wk_uu      = (const float*)d_in[31];
  const float* Wv_uu      = (const float*)d_in[32];
  const float* p_uu       = (const float*)d_in[33];
  const float* W_out_user = (const float*)d_in[34];
  const float* b_out_user = (const float*)d_in[35];
  const float* skip_user  = (const float*)d_in[38];
  const float* W_fin      = (const float*)d_in[40];
  const float* b_fin      = (const float*)d_in[41];
  float* out = (float*)d_out;

  // ---------------- workspace ----------------
  char* base = (char*)d_ws;
  size_t off = 0;
  auto alloc = [&](size_t bytes) { char* p = base + off; off += (bytes + 255) & ~(size_t)255; return p; };

  float* h       = (float*)alloc((size_t)NU * 64 * 4);
  float* als1    = (float*)alloc((size_t)NU * 4 * 4);
  float* ald1    = (float*)alloc((size_t)NU * 4 * 4);
  float* als2    = (float*)alloc((size_t)NU * 4 * 4);
  float* ald2    = (float*)alloc((size_t)NU * 4 * 4);
  float* colpart2= (float*)alloc(128 * 4);
  float* semv    = (float*)alloc(64);
  float* ball_u  = (float*)alloc(768 * 4);
  float* ball_d  = (float*)alloc(512 * 4);

  int* cnt   = (int*)alloc((size_t)3 * NU * 4);
  int* rs    = (int*)alloc((size_t)3 * NUP * 4);
  int* csums = (int*)alloc((size_t)3 * NCH * 4);
  int* coffs = (int*)alloc((size_t)3 * NCH * 4);
  int* esrcH = (int*)alloc((size_t)2 * NEDGE * 4);
  float* aevH= (float*)alloc((size_t)2 * NEDGE * 4 * 4);
  int* esrc1 = (int*)alloc((size_t)NEDGE * 4);
  float* aev1= (float*)alloc((size_t)NEDGE * 4 * 4);
  int* esrc2 = (int*)alloc((size_t)NEDGE * 4);
  float* aev2= (float*)alloc((size_t)NEDGE * 4 * 4);

  unsigned short* obf1 = (unsigned short*)alloc((size_t)NUP * 64 * 2);
  unsigned short* obf2 = (unsigned short*)alloc((size_t)NUP * 64 * 2);

  unsigned short* qukvb = (unsigned short*)alloc((size_t)NUP * 768 * 2);
  unsigned short* kvdb  = (unsigned short*)alloc((size_t)NDP * 512 * 2);

  unsigned short* xub2d = (unsigned short*)alloc((size_t)NUP * 256 * 2);
  unsigned short* xdb2d = (unsigned short*)alloc((size_t)NDP * 256 * 2);

  unsigned short* houtb = (unsigned short*)alloc((size_t)NUP * 256 * 2);
  unsigned short* xrb   = houtb;

  unsigned short* afinb = (unsigned short*)alloc((size_t)NUP * 320 * 2);
  unsigned short* xub   = afinb;
  unsigned short* xdb   = afinb + (size_t)NUP * 128;

  unsigned short* Btu_in  = (unsigned short*)alloc(256 * 128 * 2);
  unsigned short* Btd_in  = (unsigned short*)alloc(256 * 128 * 2);
  unsigned short* Btall_u = (unsigned short*)alloc(768 * 256 * 2);
  unsigned short* Btall_d = (unsigned short*)alloc(512 * 256 * 2);
  unsigned short* Bto     = (unsigned short*)alloc(256 * 256 * 2);
  unsigned short* Btf     = (unsigned short*)alloc(256 * 320 * 2);
  unsigned short* Bth     = (unsigned short*)alloc(128 * 128 * 2);
  unsigned short* BtWk    = (unsigned short*)alloc(128 * 64 * 2);

  const int B = 256;
  dim3 blk(B);
  auto g1 = [](size_t n) { return dim3((unsigned)((n + 255) / 256)); };
  auto gg = [](int N, int Mblk) {
    int Nx = (N + 127) / 128;
    return dim3((unsigned)(((Mblk + 7) / 8) * 8 * Nx));
  };

  // ===== prep: converts + weight transforms =====
  conv_pad<<<g1((size_t)NUP * 128), blk, 0, stream>>>(x_user, xub, NU, 128, NUP * 128);
  conv_pad<<<g1((size_t)NDP * 128), blk, 0, stream>>>(x_drug, xdb, ND, 128, NDP * 128);
  conv_pad<<<g1((size_t)NUP * 128), blk, 0, stream>>>(x_user_ref, xrb, NU, 128, NUP * 128);

  transp_conv<<<g1(256 * 128), blk, 0, stream>>>(W_in_user, 256, 0, Btu_in, 128, 256, 256 * 128);
  transp_conv<<<g1(256 * 128), blk, 0, stream>>>(W_in_drug, 256, 0, Btd_in, 128, 256, 256 * 128);
  transp_conv<<<g1(256 * 256), blk, 0, stream>>>(W_kqv_user, 768, 256, Btall_u + 256 * 256, 256, 256, 256 * 256);
  transp_conv<<<g1(256 * 256), blk, 0, stream>>>(W_out_user, 256, 0, Bto, 256, 256, 256 * 256);
  transp_conv<<<g1(256 * 320), blk, 0, stream>>>(W_fin, 256, 0, Btf, 320, 256, 256 * 320);
  transp_conv<<<g1(128 * 128), blk, 0, stream>>>(W_han, 64, 0, Bth, 128, 64, 128 * 128);
  transp_conv<<<g1(128 * 64), blk, 0, stream>>>(Wk_sem, 64, 0, BtWk, 64, 64, 128 * 64);

  comb_w_t<<<256, blk, 0, stream>>>(W_kqv_user, 0,   Wk_uu, Btall_u);
  comb_w_t<<<256, blk, 0, stream>>>(W_kqv_user, 512, Wv_uu, Btall_u + 512 * 256);
  comb_w_t<<<256, blk, 0, stream>>>(W_kqv_drug, 0,   Wk_du, Btall_d);
  comb_w_t<<<256, blk, 0, stream>>>(W_kqv_drug, 512, Wv_du, Btall_d + 256 * 256);
  comb_b<<<1, blk, 0, stream>>>(b_kqv_user, 0,   Wk_uu, ball_u);
  copy_f32<<<1, blk, 0, stream>>>(b_kqv_user + 256, ball_u + 256, 256);
  comb_b<<<1, blk, 0, stream>>>(b_kqv_user, 512, Wv_uu, ball_u + 512);
  comb_b<<<1, blk, 0, stream>>>(b_kqv_drug, 0,   Wk_du, ball_d);
  comb_b<<<1, blk, 0, stream>>>(b_kqv_drug, 512, Wv_du, ball_d + 256);

  // ===== CSR build =====
  hipMemsetAsync(cnt, 0, (size_t)3 * NU * 4, stream);
  hist_dst<<<g1(NEDGE), blk, 0, stream>>>(ei_du, NEDGE, cnt);
  hist_dst<<<g1(NEDGE), blk, 0, stream>>>(ei_uu, NEDGE, cnt);
  hist_dst<<<g1(NEDGE), blk, 0, stream>>>(ei_r1, NEDGE, cnt + NU);
  hist_dst<<<g1(NEDGE), blk, 0, stream>>>(ei_r2, NEDGE, cnt + 2 * NU);
  scan_partial<<<3 * NCH, blk, 0, stream>>>(cnt, csums);
  scan_mid<<<1, 64, 0, stream>>>(csums, coffs, rs);
  scan_final<<<3 * NCH, blk, 0, stream>>>(cnt, coffs, rs);
  hipMemsetAsync(cnt, 0, (size_t)3 * NU * 4, stream);
  hipMemsetAsync(colpart2, 0, 128 * 4, stream);

  // ===== HAN branch =====
  gemm_bf16<0><<<gg(64, 313), blk, 0, stream>>>(
      xrb, Bth, b_han, h, 64, (unsigned short*)nullptr, 0, NU, 64, 128, 313, nullptr, nullptr);

  han_alsd<<<g1((size_t)NU * 4), blk, 0, stream>>>(
      h, a_src_r1, a_dst_r1, a_src_r2, a_dst_r2, als1, ald1, als2, ald2);

  han_fill<<<g1((size_t)NEDGE * 4), blk, 0, stream>>>(ei_r1, NEDGE, als1, ald1,
      rs + NUP, cnt + NU, esrc1, aev1);
  han_fill<<<g1((size_t)NEDGE * 4), blk, 0, stream>>>(ei_r2, NEDGE, als2, ald2,
      rs + 2 * NUP, cnt + 2 * NU, esrc2, aev2);
  han_gather<<<g1((size_t)NUP * 64), blk, 0, stream>>>(rs + NUP, esrc1, aev1, h, obf1);
  han_gather<<<g1((size_t)NUP * 64), blk, 0, stream>>>(rs + 2 * NUP, esrc2, aev2, h, obf2);

  gemm_bf16<2><<<gg(64, 313), blk, 0, stream>>>(
      obf1, BtWk, bk_sem, colpart2, 0, (unsigned short*)nullptr, 0, NU, 64, 64, 313, nullptr, nullptr);
  gemm_bf16<2><<<gg(64, 313), blk, 0, stream>>>(
      obf2, BtWk, bk_sem, colpart2 + 64, 0, (unsigned short*)nullptr, 0, NU, 64, 64, 313, nullptr, nullptr);
  sem_final2<<<1, 128, 0, stream>>>(colpart2, q_sem, semv);

  // ===== HGT GEMMs =====
  gemm_bf16<1><<<gg(256, 313), blk, 0, stream>>>(
      xub, Btu_in, b_in_user, (float*)nullptr, 0, xub2d, 256, NU, 256, 128, 313, nullptr, nullptr);
  gemm_bf16<1><<<gg(256, 157), blk, 0, stream>>>(
      xdb, Btd_in, b_in_drug, (float*)nullptr, 0, xdb2d, 256, ND, 256, 128, 157, nullptr, nullptr);

  gemm_bf16<0><<<gg(768, 313), blk, 0, stream>>>(
      xub2d, Btall_u, ball_u, (float*)nullptr, 0, qukvb, 768, NU, 768, 256, 313, nullptr, nullptr);
  gemm_bf16<0><<<gg(512, 157), blk, 0, stream>>>(
      xdb2d, Btall_d, ball_d, (float*)nullptr, 0, kvdb, 512, ND, 512, 256, 157, nullptr, nullptr);

  // ===== HGT attention =====
  hgt_fill<<<g1((size_t)NEDGE * 4), blk, 0, stream>>>(ei_du, NEDGE,
      qukvb, kvdb, 512, NUP * 768 + 256, p_du, rs, cnt, esrcH, aevH);
  hgt_fill<<<g1((size_t)NEDGE * 4), blk, 0, stream>>>(ei_uu, NEDGE,
      qukvb, qukvb, 768, 512, p_uu, rs, cnt, esrcH, aevH);
  hgt_gather<<<g1((size_t)NUP * 64), blk, 0, stream>>>(rs, esrcH, aevH, qukvb, houtb);

  // ===== output head =====
  hipMemsetAsync(afinb + (size_t)NU * 320, 0, (size_t)(NUP - NU) * 320 * 2, stream);
  gemm_bf16<3><<<gg(256, 313), blk, 0, stream>>>(
      houtb, Bto, b_out_user, (float*)nullptr, 0, afinb, 320, NU, 256, 256, 313, skip_user, xub2d);
  fill_ref_b<<<g1((size_t)NU * 64), blk, 0, stream>>>(obf1, obf2, semv, afinb);

  gemm_bf16<0><<<gg(256, 313), blk, 0, stream>>>(
      afinb, Btf, b_fin, out, 256, (unsigned short*)nullptr, 0, NU, 256, 320, 313, nullptr, nullptr);
}

// Round 8
// 372.300 us; speedup vs baseline: 1.2887x; 1.2887x over previous
//
#include <hip/hip_runtime.h>
#include <hip/hip_bf16.h>

#define NU 40000
#define ND 20000
#define NUP 40064   // 313*128
#define NDP 20096   // 157*128
#define HIDC 256
#define NHEAD 4
#define NEDGE 80000
#define CHUNK 2048
#define NCH 20      // ceil(NU/CHUNK)

typedef __attribute__((ext_vector_type(8))) short bf16x8;
typedef __attribute__((ext_vector_type(8))) unsigned short u16x8;
typedef __attribute__((ext_vector_type(4))) float f32x4;

static __device__ __forceinline__ float b2f(unsigned short u) {
  union { unsigned int u; float f; } x; x.u = (unsigned int)u << 16; return x.f;
}
static __device__ __forceinline__ unsigned short f2b(float f) {
  union { float f; unsigned int u; } x; x.f = f;
  unsigned int r = x.u + 0x7FFFu + ((x.u >> 16) & 1u);
  return (unsigned short)(r >> 16);
}

static __device__ __forceinline__ void gload_lds16(const void* g, void* l) {
  __builtin_amdgcn_global_load_lds((const __attribute__((address_space(1))) unsigned int*)g,
                                   (__attribute__((address_space(3))) unsigned int*)l, 16, 0, 0);
}

// ============ bf16 MFMA GEMM: C = act(A @ Bt^T + bias) ============
// A: [Mpad][K] bf16. Bt: [Npad][K] bf16. 1D grid = ceil(Mblk/8)*8*Nx, 256 thr.
// XCD-colocating swizzle: all Nx col-blocks of a row-panel share id mod 8.
// ACT 0: none, 1: relu, 2: tanh+colsum->atomicAdd(Cf[col]),
// ACT 3: skip-mix: Cb = f2b(su*(acc+bias) + (1-su)*b2f(xprev)) (bf16)
// Epilogue: 2x 64-row LDS chunks, layout lrow*142 + 17*(col>>4) + (col&15):
//   writer <=2-way banks, reader <=2-way; ACT transforms applied in READ phase
//   (xprev load is a coalesced u16x8 per thread).
template<int ACT>
__global__ __launch_bounds__(256)
void gemm_bf16(const unsigned short* __restrict__ A,
               const unsigned short* __restrict__ Bt,
               const float* __restrict__ bias,
               float* __restrict__ Cf, int ldcf,
               unsigned short* __restrict__ Cb, int ldcb,
               int M, int N, int K, int Mblk,
               const float* __restrict__ skipp,
               const unsigned short* __restrict__ xprev)
{
  __shared__ __attribute__((aligned(128))) unsigned char smem[36352];
  unsigned short* ldsA = (unsigned short*)smem;
  unsigned short* ldsB = ldsA + 8192;
  float* ldsE = (float*)smem;   // epilogue overlay: 64 rows x 142 words = 36352B

  const int Nx = (N + 127) >> 7;
  const int S = Nx << 3;
  const int flat = blockIdx.x;
  const int jj = flat % S, kq = flat / S;
  const int bx = jj >> 3, by = (kq << 3) + (jj & 7);
  if (by >= Mblk) return;

  const int tid  = threadIdx.x;
  const int lane = tid & 63, wv = tid >> 6;
  const int row0 = by * 128, col0 = bx * 128;

  const int rS = wv * 32 + (lane >> 3);
  const int sS = (lane & 7) ^ (lane >> 3);

  const int lr = lane & 15, lk = lane >> 4;
  const int wr = wv >> 1, wc = wv & 1;
  const int swz = lr & 7;

  f32x4 acc[4][4] = {};

  for (int k0 = 0; k0 < K; k0 += 64) {
#pragma unroll
    for (int i = 0; i < 4; i++) {
      size_t ga = (size_t)(row0 + rS + i * 8) * K + k0 + sS * 8;
      gload_lds16(A + ga, ldsA + wv * 2048 + i * 512);
      size_t gb = (size_t)(col0 + rS + i * 8) * K + k0 + sS * 8;
      gload_lds16(Bt + gb, ldsB + wv * 2048 + i * 512);
    }
    __syncthreads();
#pragma unroll
    for (int half = 0; half < 2; half++) {
      const int k8 = half * 4 + lk;
      const int so = (k8 ^ swz) << 3;
      bf16x8 av[4], bv[4];
#pragma unroll
      for (int m = 0; m < 4; m++)
        av[m] = *(const bf16x8*)&ldsA[(wr * 64 + m * 16 + lr) * 64 + so];
#pragma unroll
      for (int n = 0; n < 4; n++)
        bv[n] = *(const bf16x8*)&ldsB[(wc * 64 + n * 16 + lr) * 64 + so];
#pragma unroll
      for (int m = 0; m < 4; m++)
#pragma unroll
        for (int n = 0; n < 4; n++)
          acc[m][n] = __builtin_amdgcn_mfma_f32_16x16x32_bf16(av[m], bv[n], acc[m][n], 0, 0, 0);
    }
    __syncthreads();
  }

  if (ACT == 2) {
    __shared__ float csum[64];
    if (tid < 64) csum[tid] = 0.f;
    __syncthreads();
#pragma unroll
    for (int n = 0; n < 4; n++) {
      int col = col0 + wc * 64 + n * 16 + lr;
      if (col < N) {
        float bi = bias[col];
        float local = 0.f;
#pragma unroll
        for (int m = 0; m < 4; m++)
#pragma unroll
          for (int g = 0; g < 4; g++) {
            int row = row0 + wr * 64 + m * 16 + lk * 4 + g;
            if (row < M) local += tanhf(acc[m][n][g] + bi);
          }
        atomicAdd(&csum[col], local);
      }
    }
    __syncthreads();
    if (tid < 64) atomicAdd(&Cf[tid], csum[tid]);
    return;
  }

  float su = 0.f;
  if (ACT == 3) su = 1.f / (1.f + expf(-skipp[0]));
  float bi[4];
#pragma unroll
  for (int n = 0; n < 4; n++) {
    int col = col0 + wc * 64 + n * 16 + lr;
    bi[n] = (col < N) ? bias[col] : 0.f;
  }

#pragma unroll
  for (int ch = 0; ch < 2; ch++) {
    __syncthreads();
    if (wr == ch) {
#pragma unroll
      for (int m = 0; m < 4; m++)
#pragma unroll
        for (int n = 0; n < 4; n++)
#pragma unroll
          for (int g = 0; g < 4; g++) {
            int lrow = m * 16 + lk * 4 + g;
            ldsE[lrow * 142 + 17 * (4 * wc + n) + lr] = acc[m][n][g] + bi[n];
          }
    }
    __syncthreads();
#pragma unroll
    for (int i = 0; i < 4; i++) {
      int c = tid + i * 256;            // 0..1023 over 64 rows x 16 col-chunks
      int lrow = c >> 4, cc = c & 15;
      int row = row0 + ch * 64 + lrow;
      int colb = cc * 8;
      float v[8];
#pragma unroll
      for (int q = 0; q < 8; q++)
        v[q] = ldsE[lrow * 142 + 17 * (cc >> 1) + 8 * (cc & 1) + q];
      if (ACT == 1) {
#pragma unroll
        for (int q = 0; q < 8; q++) v[q] = fmaxf(v[q], 0.f);
      }
      if (ACT == 3) {
        u16x8 xp = *(const u16x8*)(xprev + (size_t)row * 256 + col0 + colb);
#pragma unroll
        for (int q = 0; q < 8; q++) v[q] = su * v[q] + (1.f - su) * b2f(xp[q]);
      }
      if (Cb) {
        u16x8 o;
#pragma unroll
        for (int q = 0; q < 8; q++) o[q] = f2b(row < M ? v[q] : 0.f);
        *(u16x8*)(Cb + (size_t)row * ldcb + col0 + colb) = o;
      }
      if (Cf && row < M) {
        int col = col0 + colb;
        if (col < N)
          *(float4*)&Cf[(size_t)row * ldcf + col] = make_float4(v[0], v[1], v[2], v[3]);
        if (col + 4 < N)
          *(float4*)&Cf[(size_t)row * ldcf + col + 4] = make_float4(v[4], v[5], v[6], v[7]);
      }
    }
  }
}

// ============ fused prep: all converts + weight transforms in one kernel ============
__global__ __launch_bounds__(256)
void prep_all(const float* __restrict__ x_user, const float* __restrict__ x_drug,
              const float* __restrict__ x_user_ref,
              const float* __restrict__ W_in_user, const float* __restrict__ W_in_drug,
              const float* __restrict__ W_kqv_user, const float* __restrict__ W_kqv_drug,
              const float* __restrict__ W_out_user, const float* __restrict__ W_fin,
              const float* __restrict__ W_han, const float* __restrict__ Wk_sem,
              const float* __restrict__ Wk_uu, const float* __restrict__ Wv_uu,
              const float* __restrict__ Wk_du, const float* __restrict__ Wv_du,
              const float* __restrict__ b_kqv_user, const float* __restrict__ b_kqv_drug,
              unsigned short* __restrict__ xub, unsigned short* __restrict__ xdb,
              unsigned short* __restrict__ xrb,
              unsigned short* __restrict__ Btu_in, unsigned short* __restrict__ Btd_in,
              unsigned short* __restrict__ Btall_u, unsigned short* __restrict__ Btall_d,
              unsigned short* __restrict__ Bto, unsigned short* __restrict__ Btf,
              unsigned short* __restrict__ Bth, unsigned short* __restrict__ BtWk,
              float* __restrict__ ball_u, float* __restrict__ ball_d)
{
  size_t t = (size_t)blockIdx.x * 256 + threadIdx.x;
  const size_t c0 = (size_t)NUP * 128;          // xub
  const size_t c1 = c0 + (size_t)NDP * 128;     // xdb
  const size_t c2 = c1 + (size_t)NUP * 128;     // xrb
  const size_t c3 = c2 + 32768;                 // Btu_in (K128,N256)
  const size_t c4 = c3 + 32768;                 // Btd_in
  const size_t c5 = c4 + 65536;                 // Btq -> Btall_u+65536 (K256,N256,coloff256,ldw768)
  const size_t c6 = c5 + 65536;                 // Bto
  const size_t c7 = c6 + 81920;                 // Btf (K320,N256,ldw256)
  const size_t c8 = c7 + 16384;                 // Bth (K128,N64 pad->128)
  const size_t c9 = c8 + 8192;                  // BtWk (K64,N64 pad->128)
  const size_t c10 = c9 + 65536;                // comb ku -> Btall_u
  const size_t c11 = c10 + 65536;               // comb vu -> Btall_u+131072
  const size_t c12 = c11 + 65536;               // comb kd -> Btall_d
  const size_t c13 = c12 + 65536;               // comb vd -> Btall_d+65536
  const size_t c14 = c13 + 1280;                // biases
  if (t >= c14) return;

  if (t < c2) {  // conv_pad x3
    const float* in; unsigned short* outp; int M; size_t i;
    if (t < c0)      { in = x_user;     outp = xub; M = NU; i = t; }
    else if (t < c1) { in = x_drug;     outp = xdb; M = ND; i = t - c0; }
    else             { in = x_user_ref; outp = xrb; M = NU; i = t - c1; }
    int r = (int)(i >> 7);
    outp[i] = (r < M) ? f2b(in[i]) : 0;
    return;
  }
  if (t < c9) {  // transp_conv x7
    const float* W; unsigned short* Bt; int ldw, coloff, K, N; size_t i;
    if (t < c3)      { W = W_in_user;  Bt = Btu_in;          ldw = 256; coloff = 0;   K = 128; N = 256; i = t - c2; }
    else if (t < c4) { W = W_in_drug;  Bt = Btd_in;          ldw = 256; coloff = 0;   K = 128; N = 256; i = t - c3; }
    else if (t < c5) { W = W_kqv_user; Bt = Btall_u + 65536; ldw = 768; coloff = 256; K = 256; N = 256; i = t - c4; }
    else if (t < c6) { W = W_out_user; Bt = Bto;             ldw = 256; coloff = 0;   K = 256; N = 256; i = t - c5; }
    else if (t < c7) { W = W_fin;      Bt = Btf;             ldw = 256; coloff = 0;   K = 320; N = 256; i = t - c6; }
    else if (t < c8) { W = W_han;      Bt = Bth;             ldw = 64;  coloff = 0;   K = 128; N = 64;  i = t - c7; }
    else             { W = Wk_sem;     Bt = BtWk;            ldw = 64;  coloff = 0;   K = 64;  N = 64;  i = t - c8; }
    int n = (int)(i / K), k = (int)(i - (size_t)n * K);
    Bt[i] = (n < N) ? f2b(W[(size_t)k * ldw + coloff + n]) : 0;
    return;
  }
  if (t < c13) {  // comb_w_t x4
    const float* Wkqv; const float* Wh; unsigned short* Bt; int coloff; size_t i;
    if (t < c10)      { Wkqv = W_kqv_user; Wh = Wk_uu; Bt = Btall_u;          coloff = 0;   i = t - c9; }
    else if (t < c11) { Wkqv = W_kqv_user; Wh = Wv_uu; Bt = Btall_u + 131072; coloff = 512; i = t - c10; }
    else if (t < c12) { Wkqv = W_kqv_drug; Wh = Wk_du; Bt = Btall_d;          coloff = 0;   i = t - c11; }
    else              { Wkqv = W_kqv_drug; Wh = Wv_du; Bt = Btall_d + 65536;  coloff = 512; i = t - c12; }
    int n = (int)(i >> 8), c = (int)(i & 255);
    int hh = n >> 6, e = n & 63;
    float acc = 0.f;
    for (int d = 0; d < 64; d++)
      acc += Wkqv[(size_t)c * 768 + coloff + hh * 64 + d] * Wh[hh * 4096 + d * 64 + e];
    Bt[i] = f2b(acc);
    return;
  }
  { // biases (1280)
    int j = (int)(t - c13);
    const float* b; const float* Wh; float* outp; int coloff, e256;
    if (j < 256)       { outp = &ball_u[j];        b = b_kqv_user; Wh = Wk_uu; coloff = 0;   e256 = j; }
    else if (j < 512)  { ball_u[j] = b_kqv_user[j]; return; }
    else if (j < 768)  { outp = &ball_u[j];        b = b_kqv_user; Wh = Wv_uu; coloff = 512; e256 = j - 512; }
    else if (j < 1024) { outp = &ball_d[j - 768];  b = b_kqv_drug; Wh = Wk_du; coloff = 0;   e256 = j - 768; }
    else               { outp = &ball_d[j - 768];  b = b_kqv_drug; Wh = Wv_du; coloff = 512; e256 = j - 1024; }
    int hh = e256 >> 6, e = e256 & 63;
    float acc = 0.f;
    for (int d = 0; d < 64; d++)
      acc += b[coloff + hh * 64 + d] * Wh[hh * 4096 + d * 64 + e];
    *outp = acc;
  }
}

// ============ CSR build ============
__global__ void hist_all(const int* __restrict__ ei_du, const int* __restrict__ ei_uu,
                         const int* __restrict__ ei_r1, const int* __restrict__ ei_r2,
                         int* __restrict__ cnt)
{
  int t = blockIdx.x * 256 + threadIdx.x;
  if (t >= NEDGE) return;
  const int* ei; int* c;
  switch (blockIdx.y) {
    case 0: ei = ei_du; c = cnt; break;
    case 1: ei = ei_uu; c = cnt; break;
    case 2: ei = ei_r1; c = cnt + NU; break;
    default: ei = ei_r2; c = cnt + 2 * NU; break;
  }
  atomicAdd(&c[ei[NEDGE + t]], 1);
}

__global__ __launch_bounds__(256)
void scan_partial(const int* __restrict__ cnt, int* __restrict__ csums)
{
  int b = blockIdx.x;
  int rel = b / NCH, ch = b - rel * NCH;
  const int* c = cnt + (size_t)rel * NU;
  int t = threadIdx.x;
  int i0 = ch * CHUNK + t * 8;
  int s = 0;
#pragma unroll
  for (int j = 0; j < 8; j++) { int i = i0 + j; if (i < NU) s += c[i]; }
  __shared__ int ps[256];
  ps[t] = s;
  __syncthreads();
  for (int d = 128; d > 0; d >>= 1) { if (t < d) ps[t] += ps[t + d]; __syncthreads(); }
  if (t == 0) csums[b] = ps[0];
}

__global__ void scan_mid(const int* __restrict__ csums, int* __restrict__ coffs,
                         int* __restrict__ rs)
{
  int r = threadIdx.x;
  if (r >= 3) return;
  int run = 0;
  for (int ch = 0; ch < NCH; ch++) { coffs[r * NCH + ch] = run; run += csums[r * NCH + ch]; }
  rs[(size_t)r * NUP + NU] = run;
}

__global__ __launch_bounds__(256)
void scan_final(const int* __restrict__ cnt, const int* __restrict__ coffs,
                int* __restrict__ rs)
{
  int b = blockIdx.x;
  int rel = b / NCH, ch = b - rel * NCH;
  const int* c = cnt + (size_t)rel * NU;
  int* r = rs + (size_t)rel * NUP;
  int t = threadIdx.x;
  int i0 = ch * CHUNK + t * 8;
  int loc[8]; int s = 0;
#pragma unroll
  for (int j = 0; j < 8; j++) { int i = i0 + j; loc[j] = (i < NU) ? c[i] : 0; s += loc[j]; }
  __shared__ int ps[256];
  ps[t] = s;
  __syncthreads();
  for (int d = 1; d < 256; d <<= 1) {
    int o = (t >= d) ? ps[t - d] : 0;
    __syncthreads();
    ps[t] += o;
    __syncthreads();
  }
  int run = coffs[b] + ps[t] - s;
#pragma unroll
  for (int j = 0; j < 8; j++) { int i = i0 + j; if (i < NU) { r[i] = run; run += loc[j]; } }
}

// ============ HAN ============
__global__ void han_alsd(const float* __restrict__ h,
                         const float* __restrict__ a_s1, const float* __restrict__ a_d1,
                         const float* __restrict__ a_s2, const float* __restrict__ a_d2,
                         float* __restrict__ als1, float* __restrict__ ald1,
                         float* __restrict__ als2, float* __restrict__ ald2)
{
  int t = blockIdx.x * 256 + threadIdx.x;
  if (t >= NU * NHEAD) return;
  int n = t >> 2, hh = t & 3;
  const float* hp = h + (size_t)n * 64 + hh * 16;
  float s1 = 0, d1 = 0, s2 = 0, d2 = 0;
#pragma unroll
  for (int d = 0; d < 16; d++) {
    float v = hp[d];
    s1 += v * a_s1[hh * 16 + d]; d1 += v * a_d1[hh * 16 + d];
    s2 += v * a_s2[hh * 16 + d]; d2 += v * a_d2[hh * 16 + d];
  }
  als1[t] = s1; ald1[t] = d1; als2[t] = s2; ald2[t] = d2;
}

// merged: y=0 -> relation 1, y=1 -> relation 2
__global__ void han_fill2(const int* __restrict__ ei1, const int* __restrict__ ei2,
                          const float* __restrict__ als1, const float* __restrict__ ald1,
                          const float* __restrict__ als2, const float* __restrict__ ald2,
                          const int* __restrict__ rs, int* __restrict__ cur,
                          int* __restrict__ esrc1, float* __restrict__ aev1,
                          int* __restrict__ esrc2, float* __restrict__ aev2)
{
  int t = blockIdx.x * 256 + threadIdx.x;
  if (t >= NEDGE * 4) return;
  int y = blockIdx.y;
  const int* ei = y ? ei2 : ei1;
  const float* als = y ? als2 : als1;
  const float* ald = y ? ald2 : ald1;
  const int* rsp = rs + (size_t)(y + 1) * NUP - NUP * 0;  // rs1 at +NUP, rs2 at +2*NUP handled below
  rsp = rs + (size_t)(y ? 2 : 1) * NUP;
  int* curp = cur + (size_t)(y ? 2 : 1) * NU;
  int* esrc = y ? esrc2 : esrc1;
  float* aev = y ? aev2 : aev1;
  int e = t >> 2, hh = t & 3;
  int s = ei[e], d = ei[NEDGE + e];
  float al = als[s * 4 + hh] + ald[d * 4 + hh];
  al = (al >= 0.f) ? al : 0.2f * al;
  float ex = expf(al);
  int pos = 0;
  if (hh == 0) pos = rsp[d] + atomicAdd(&curp[d], 1);
  pos = __shfl(pos, (threadIdx.x & 63) & ~3, 64);
  aev[pos * 4 + hh] = ex;
  if (hh == 0) esrc[pos] = s;
}

// merged: one wave per dst row, y selects relation
__global__ __launch_bounds__(256)
void han_gather2(const int* __restrict__ rs,
                 const int* __restrict__ esrc1, const float* __restrict__ aev1,
                 const int* __restrict__ esrc2, const float* __restrict__ aev2,
                 const float* __restrict__ h,
                 unsigned short* __restrict__ obf1, unsigned short* __restrict__ obf2)
{
  int gid = blockIdx.x * 256 + threadIdx.x;
  int wid = gid >> 6, lane = gid & 63;
  if (wid >= NUP) return;
  int y = blockIdx.y;
  const int* rsp = rs + (size_t)(y ? 2 : 1) * NUP;
  const int* esrc = y ? esrc2 : esrc1;
  const float* aev = y ? aev2 : aev1;
  unsigned short* obf = y ? obf2 : obf1;
  int head = lane >> 4;
  int beg = 0, end = 0;
  if (wid < NU) { beg = rsp[wid]; end = rsp[wid + 1]; }
  float asum = 0.f;
  for (int i = beg; i < end; i++) asum += aev[i * 4 + head];
  float inv = 1.f / (asum + 1e-16f);
  float a = 0.f;
  for (int i = beg; i < end; i++)
    a += aev[i * 4 + head] * inv * h[(size_t)esrc[i] * 64 + lane];
  obf[(size_t)wid * 64 + lane] = f2b(fmaxf(a, 0.f));
}

__global__ void sem_final2(const float* __restrict__ colpart2,
                           const float* __restrict__ q_sem, float* __restrict__ semv)
{
  int t = threadIdx.x;            // 128
  int j = t & 63;
  __shared__ float sv[128];
  sv[t] = colpart2[t] * q_sem[j] * (1.0f / NU);
  __syncthreads();
  if (t == 0) {
    float s0 = 0, s1 = 0;
    for (int i = 0; i < 64; i++) { s0 += sv[i]; s1 += sv[64 + i]; }
    float m = fmaxf(s0, s1);
    float e0 = expf(s0 - m), e1 = expf(s1 - m);
    semv[0] = e0 / (e0 + e1); semv[1] = e1 / (e0 + e1);
  }
}

// ============ HGT ============
// merged: y=0 -> du edges (k from kvdb), y=1 -> uu edges (k from qukvb)
__global__ void hgt_fill2(const int* __restrict__ ei_du, const int* __restrict__ ei_uu,
                          const unsigned short* __restrict__ qb,
                          const unsigned short* __restrict__ kvdb,
                          const float* __restrict__ p_du, const float* __restrict__ p_uu,
                          const int* __restrict__ rs, int* __restrict__ cur,
                          int* __restrict__ esrc, float* __restrict__ aev)
{
  int t = blockIdx.x * 256 + threadIdx.x;
  if (t >= NEDGE * 4) return;
  int y = blockIdx.y;
  const int* ei = y ? ei_uu : ei_du;
  const unsigned short* kb = y ? qb : kvdb;
  const int ks = y ? 768 : 512;
  const int voff = y ? 512 : NUP * 768 + 256;
  const float* p = y ? p_uu : p_du;
  int e = t >> 2, hh = t & 3;
  int s = ei[e], d = ei[NEDGE + e];
  const uint4* qv = (const uint4*)(qb + (size_t)d * 768 + 256 + hh * 64);
  const uint4* kv = (const uint4*)(kb + (size_t)s * ks + hh * 64);
  float acc = 0.f;
#pragma unroll
  for (int i = 0; i < 8; i++) {
    uint4 a = qv[i], b = kv[i];
    unsigned int aw[4] = {a.x, a.y, a.z, a.w};
    unsigned int bw[4] = {b.x, b.y, b.z, b.w};
#pragma unroll
    for (int u = 0; u < 4; u++) {
      acc += b2f((unsigned short)(aw[u] & 0xffff)) * b2f((unsigned short)(bw[u] & 0xffff));
      acc += b2f((unsigned short)(aw[u] >> 16))    * b2f((unsigned short)(bw[u] >> 16));
    }
  }
  float ex = expf(acc * p[hh] * 0.125f);
  int pos = 0;
  if (hh == 0) pos = rs[d] + atomicAdd(&cur[d], 1);
  pos = __shfl(pos, (threadIdx.x & 63) & ~3, 64);
  aev[pos * 4 + hh] = ex;
  if (hh == 0) esrc[pos] = voff + s * ks;
}

__global__ __launch_bounds__(256)
void hgt_gather(const int* __restrict__ rs, const int* __restrict__ esrc,
                const float* __restrict__ aev, const unsigned short* __restrict__ vbase,
                unsigned short* __restrict__ houtb)
{
  int gid = blockIdx.x * 256 + threadIdx.x;
  int wid = gid >> 6, lane = gid & 63;
  if (wid >= NUP) return;
  int head = lane >> 4;
  int beg = 0, end = 0;
  if (wid < NU) { beg = rs[wid]; end = rs[wid + 1]; }
  float asum = 0.f;
  for (int i = beg; i < end; i++) asum += aev[i * 4 + head];
  float inv = 1.f / (asum + 1e-16f);
  float a0 = 0, a1 = 0, a2 = 0, a3 = 0;
  for (int i = beg; i < end; i++) {
    float w = aev[i * 4 + head] * inv;
    const ushort4 v = *(const ushort4*)(vbase + (size_t)esrc[i] + lane * 4);
    a0 += b2f(v.x) * w; a1 += b2f(v.y) * w; a2 += b2f(v.z) * w; a3 += b2f(v.w) * w;
  }
  ushort4 o;
  o.x = f2b(0.5f * a0 * (1.f + erff(a0 * 0.70710678118654752f)));
  o.y = f2b(0.5f * a1 * (1.f + erff(a1 * 0.70710678118654752f)));
  o.z = f2b(0.5f * a2 * (1.f + erff(a2 * 0.70710678118654752f)));
  o.w = f2b(0.5f * a3 * (1.f + erff(a3 * 0.70710678118654752f)));
  *(ushort4*)(houtb + (size_t)wid * 256 + lane * 4) = o;
}

// ============ epilogues ============
// covers ALL NUP rows (zero for pad) -> no separate memset needed
__global__ void fill_ref_b(const unsigned short* __restrict__ obf1,
                           const unsigned short* __restrict__ obf2,
                           const float* __restrict__ semv, unsigned short* __restrict__ afinb)
{
  int t = blockIdx.x * 256 + threadIdx.x;  // n*64 + j
  if (t >= NUP * 64) return;
  int n = t >> 6, j = t & 63;
  float v = semv[0] * b2f(obf1[t]) + semv[1] * b2f(obf2[t]);  // pad rows are 0
  afinb[(size_t)n * 320 + 256 + j] = f2b(v);
}

// ------------------------------------------------------------------
extern "C" void kernel_launch(void* const* d_in, const int* in_sizes, int n_in,
                              void* d_out, int out_size, void* d_ws, size_t ws_size,
                              hipStream_t stream)
{
  (void)in_sizes; (void)n_in; (void)out_size; (void)ws_size;
  const float* x_user     = (const float*)d_in[0];
  const float* x_drug     = (const float*)d_in[1];
  const float* x_user_ref = (const float*)d_in[2];
  const int*   ei_du      = (const int*)d_in[4];
  const int*   ei_uu      = (const int*)d_in[5];
  const int*   ei_r1      = (const int*)d_in[6];
  const int*   ei_r2      = (const int*)d_in[7];
  const float* W_han      = (const float*)d_in[8];
  const float* b_han      = (const float*)d_in[9];
  const float* a_src_r1   = (const float*)d_in[10];
  const float* a_dst_r1   = (const float*)d_in[11];
  const float* a_src_r2   = (const float*)d_in[12];
  const float* a_dst_r2   = (const float*)d_in[13];
  const float* Wk_sem     = (const float*)d_in[14];
  const float* bk_sem     = (const float*)d_in[15];
  const float* q_sem      = (const float*)d_in[16];
  const float* b_in_user  = (const float*)d_in[18];
  const float* b_in_drug  = (const float*)d_in[20];
  const float* W_in_user  = (const float*)d_in[17];
  const float* W_in_drug  = (const float*)d_in[19];
  const float* W_kqv_user = (const float*)d_in[21];
  const float* b_kqv_user = (const float*)d_in[22];
  const float* W_kqv_drug = (const float*)d_in[23];
  const float* b_kqv_drug = (const float*)d_in[24];
  const float* Wk_du      = (const float*)d_in[28];
  const float* Wv_du      = (const float*)d_in[29];
  const float* p_du       = (const float*)d_in[30];
  const float* Wk_uu      = (const float*)d_in[31];
  const float* Wv_uu      = (const float*)d_in[32];
  const float* p_uu       = (const float*)d_in[33];
  const float* W_out_user = (const float*)d_in[34];
  const float* b_out_user = (const float*)d_in[35];
  const float* skip_user  = (const float*)d_in[38];
  const float* W_fin      = (const float*)d_in[40];
  const float* b_fin      = (const float*)d_in[41];
  float* out = (float*)d_out;

  // ---------------- workspace ----------------
  char* base = (char*)d_ws;
  size_t off = 0;
  auto alloc = [&](size_t bytes) { char* p = base + off; off += (bytes + 255) & ~(size_t)255; return p; };

  float* h       = (float*)alloc((size_t)NU * 64 * 4);
  float* als1    = (float*)alloc((size_t)NU * 4 * 4);
  float* ald1    = (float*)alloc((size_t)NU * 4 * 4);
  float* als2    = (float*)alloc((size_t)NU * 4 * 4);
  float* ald2    = (float*)alloc((size_t)NU * 4 * 4);
  float* colpart2= (float*)alloc(128 * 4);
  float* semv    = (float*)alloc(64);
  float* ball_u  = (float*)alloc(768 * 4);
  float* ball_d  = (float*)alloc(512 * 4);

  int* cnt   = (int*)alloc((size_t)3 * NU * 4);
  int* rs    = (int*)alloc((size_t)3 * NUP * 4);
  int* csums = (int*)alloc((size_t)3 * NCH * 4);
  int* coffs = (int*)alloc((size_t)3 * NCH * 4);
  int* esrcH = (int*)alloc((size_t)2 * NEDGE * 4);
  float* aevH= (float*)alloc((size_t)2 * NEDGE * 4 * 4);
  int* esrc1 = (int*)alloc((size_t)NEDGE * 4);
  float* aev1= (float*)alloc((size_t)NEDGE * 4 * 4);
  int* esrc2 = (int*)alloc((size_t)NEDGE * 4);
  float* aev2= (float*)alloc((size_t)NEDGE * 4 * 4);

  unsigned short* obf1 = (unsigned short*)alloc((size_t)NUP * 64 * 2);
  unsigned short* obf2 = (unsigned short*)alloc((size_t)NUP * 64 * 2);

  unsigned short* qukvb = (unsigned short*)alloc((size_t)NUP * 768 * 2);
  unsigned short* kvdb  = (unsigned short*)alloc((size_t)NDP * 512 * 2);

  unsigned short* xub2d = (unsigned short*)alloc((size_t)NUP * 256 * 2);
  unsigned short* xdb2d = (unsigned short*)alloc((size_t)NDP * 256 * 2);

  unsigned short* houtb = (unsigned short*)alloc((size_t)NUP * 256 * 2);
  unsigned short* xrb   = houtb;

  unsigned short* afinb = (unsigned short*)alloc((size_t)NUP * 320 * 2);
  unsigned short* xub   = afinb;
  unsigned short* xdb   = afinb + (size_t)NUP * 128;

  unsigned short* Btu_in  = (unsigned short*)alloc(256 * 128 * 2);
  unsigned short* Btd_in  = (unsigned short*)alloc(256 * 128 * 2);
  unsigned short* Btall_u = (unsigned short*)alloc(768 * 256 * 2);
  unsigned short* Btall_d = (unsigned short*)alloc(512 * 256 * 2);
  unsigned short* Bto     = (unsigned short*)alloc(256 * 256 * 2);
  unsigned short* Btf     = (unsigned short*)alloc(256 * 320 * 2);
  unsigned short* Bth     = (unsigned short*)alloc(128 * 128 * 2);
  unsigned short* BtWk    = (unsigned short*)alloc(128 * 64 * 2);

  const int B = 256;
  dim3 blk(B);
  auto g1 = [](size_t n) { return dim3((unsigned)((n + 255) / 256)); };
  auto gg = [](int N, int Mblk) {
    int Nx = (N + 127) / 128;
    return dim3((unsigned)(((Mblk + 7) / 8) * 8 * Nx));
  };

  // ===== fused prep =====
  const size_t prep_total = (size_t)NUP * 128 * 2 + (size_t)NDP * 128
                          + 32768 * 2 + 65536 * 2 + 81920 + 16384 + 8192
                          + 65536 * 4 + 1280;
  prep_all<<<g1(prep_total), blk, 0, stream>>>(
      x_user, x_drug, x_user_ref, W_in_user, W_in_drug, W_kqv_user, W_kqv_drug,
      W_out_user, W_fin, W_han, Wk_sem, Wk_uu, Wv_uu, Wk_du, Wv_du,
      b_kqv_user, b_kqv_drug,
      xub, xdb, xrb, Btu_in, Btd_in, Btall_u, Btall_d, Bto, Btf, Bth, BtWk,
      ball_u, ball_d);

  // ===== CSR build =====
  hipMemsetAsync(cnt, 0, (size_t)3 * NU * 4, stream);
  hist_all<<<dim3((NEDGE + 255) / 256, 4), blk, 0, stream>>>(ei_du, ei_uu, ei_r1, ei_r2, cnt);
  scan_partial<<<3 * NCH, blk, 0, stream>>>(cnt, csums);
  scan_mid<<<1, 64, 0, stream>>>(csums, coffs, rs);
  scan_final<<<3 * NCH, blk, 0, stream>>>(cnt, coffs, rs);
  hipMemsetAsync(cnt, 0, (size_t)3 * NU * 4, stream);
  hipMemsetAsync(colpart2, 0, 128 * 4, stream);

  // ===== HAN branch =====
  gemm_bf16<0><<<gg(64, 313), blk, 0, stream>>>(
      xrb, Bth, b_han, h, 64, (unsigned short*)nullptr, 0, NU, 64, 128, 313, nullptr, nullptr);

  han_alsd<<<g1((size_t)NU * 4), blk, 0, stream>>>(
      h, a_src_r1, a_dst_r1, a_src_r2, a_dst_r2, als1, ald1, als2, ald2);

  han_fill2<<<dim3((NEDGE * 4 + 255) / 256, 2), blk, 0, stream>>>(
      ei_r1, ei_r2, als1, ald1, als2, ald2, rs, cnt, esrc1, aev1, esrc2, aev2);
  han_gather2<<<dim3((NUP * 64 + 255) / 256, 2), blk, 0, stream>>>(
      rs, esrc1, aev1, esrc2, aev2, h, obf1, obf2);

  gemm_bf16<2><<<gg(64, 313), blk, 0, stream>>>(
      obf1, BtWk, bk_sem, colpart2, 0, (unsigned short*)nullptr, 0, NU, 64, 64, 313, nullptr, nullptr);
  gemm_bf16<2><<<gg(64, 313), blk, 0, stream>>>(
      obf2, BtWk, bk_sem, colpart2 + 64, 0, (unsigned short*)nullptr, 0, NU, 64, 64, 313, nullptr, nullptr);
  sem_final2<<<1, 128, 0, stream>>>(colpart2, q_sem, semv);

  // ===== HGT GEMMs =====
  gemm_bf16<1><<<gg(256, 313), blk, 0, stream>>>(
      xub, Btu_in, b_in_user, (float*)nullptr, 0, xub2d, 256, NU, 256, 128, 313, nullptr, nullptr);
  gemm_bf16<1><<<gg(256, 157), blk, 0, stream>>>(
      xdb, Btd_in, b_in_drug, (float*)nullptr, 0, xdb2d, 256, ND, 256, 128, 157, nullptr, nullptr);

  gemm_bf16<0><<<gg(768, 313), blk, 0, stream>>>(
      xub2d, Btall_u, ball_u, (float*)nullptr, 0, qukvb, 768, NU, 768, 256, 313, nullptr, nullptr);
  gemm_bf16<0><<<gg(512, 157), blk, 0, stream>>>(
      xdb2d, Btall_d, ball_d, (float*)nullptr, 0, kvdb, 512, ND, 512, 256, 157, nullptr, nullptr);

  // ===== HGT attention =====
  hgt_fill2<<<dim3((NEDGE * 4 + 255) / 256, 2), blk, 0, stream>>>(
      ei_du, ei_uu, qukvb, kvdb, p_du, p_uu, rs, cnt, esrcH, aevH);
  hgt_gather<<<g1((size_t)NUP * 64), blk, 0, stream>>>(rs, esrcH, aevH, qukvb, houtb);

  // ===== output head =====
  gemm_bf16<3><<<gg(256, 313), blk, 0, stream>>>(
      houtb, Bto, b_out_user, (float*)nullptr, 0, afinb, 320, NU, 256, 256, 313, skip_user, xub2d);
  fill_ref_b<<<g1((size_t)NUP * 64), blk, 0, stream>>>(obf1, obf2, semv, afinb);

  gemm_bf16<0><<<gg(256, 313), blk, 0, stream>>>(
      afinb, Btf, b_fin, out, 256, (unsigned short*)nullptr, 0, NU, 256, 320, 313, nullptr, nullptr);
}

// Round 9
// 358.186 us; speedup vs baseline: 1.3395x; 1.0394x over previous
//
#include <hip/hip_runtime.h>
#include <hip/hip_bf16.h>

#define NU 40000
#define ND 20000
#define NUP 40064   // 313*128
#define NDP 20096   // 157*128
#define HIDC 256
#define NHEAD 4
#define NEDGE 80000
#define CHUNK 2048
#define NCH 20      // ceil(NU/CHUNK)

typedef __attribute__((ext_vector_type(8))) short bf16x8;
typedef __attribute__((ext_vector_type(8))) unsigned short u16x8;
typedef __attribute__((ext_vector_type(4))) float f32x4;

static __device__ __forceinline__ float b2f(unsigned short u) {
  union { unsigned int u; float f; } x; x.u = (unsigned int)u << 16; return x.f;
}
static __device__ __forceinline__ unsigned short f2b(float f) {
  union { float f; unsigned int u; } x; x.f = f;
  unsigned int r = x.u + 0x7FFFu + ((x.u >> 16) & 1u);
  return (unsigned short)(r >> 16);
}

static __device__ __forceinline__ void gload_lds16(const void* g, void* l) {
  __builtin_amdgcn_global_load_lds((const __attribute__((address_space(1))) unsigned int*)g,
                                   (__attribute__((address_space(3))) unsigned int*)l, 16, 0, 0);
}

// ============ bf16 MFMA GEMM: C = act(A @ Bt^T + bias) ============
// A: [Mpad][K] bf16. Bt: [Npad][K] bf16. 1D grid = ceil(Mblk/8)*8*Nx, 256 thr.
// XCD-colocating swizzle: all Nx col-blocks of a row-panel share id mod 8.
// ACT 0: none, 1: relu, 2: tanh+colsum->atomicAdd(Cf[col]),
// ACT 3: skip-mix: Cb = f2b(su*(acc+bias) + (1-su)*b2f(xprev)) (bf16)
// Epilogue: 2x 64-row LDS chunks, layout lrow*142 + 17*(col>>4) + (col&15):
//   writer <=2-way banks, reader <=2-way; ACT transforms applied in READ phase
//   (xprev load is a coalesced u16x8 per thread).
template<int ACT>
__global__ __launch_bounds__(256)
void gemm_bf16(const unsigned short* __restrict__ A,
               const unsigned short* __restrict__ Bt,
               const float* __restrict__ bias,
               float* __restrict__ Cf, int ldcf,
               unsigned short* __restrict__ Cb, int ldcb,
               int M, int N, int K, int Mblk,
               const float* __restrict__ skipp,
               const unsigned short* __restrict__ xprev)
{
  __shared__ __attribute__((aligned(128))) unsigned char smem[36352];
  unsigned short* ldsA = (unsigned short*)smem;
  unsigned short* ldsB = ldsA + 8192;
  float* ldsE = (float*)smem;   // epilogue overlay: 64 rows x 142 words = 36352B

  const int Nx = (N + 127) >> 7;
  const int S = Nx << 3;
  const int flat = blockIdx.x;
  const int jj = flat % S, kq = flat / S;
  const int bx = jj >> 3, by = (kq << 3) + (jj & 7);
  if (by >= Mblk) return;

  const int tid  = threadIdx.x;
  const int lane = tid & 63, wv = tid >> 6;
  const int row0 = by * 128, col0 = bx * 128;

  const int rS = wv * 32 + (lane >> 3);
  const int sS = (lane & 7) ^ (lane >> 3);

  const int lr = lane & 15, lk = lane >> 4;
  const int wr = wv >> 1, wc = wv & 1;
  const int swz = lr & 7;

  f32x4 acc[4][4] = {};

  for (int k0 = 0; k0 < K; k0 += 64) {
#pragma unroll
    for (int i = 0; i < 4; i++) {
      size_t ga = (size_t)(row0 + rS + i * 8) * K + k0 + sS * 8;
      gload_lds16(A + ga, ldsA + wv * 2048 + i * 512);
      size_t gb = (size_t)(col0 + rS + i * 8) * K + k0 + sS * 8;
      gload_lds16(Bt + gb, ldsB + wv * 2048 + i * 512);
    }
    __syncthreads();
#pragma unroll
    for (int half = 0; half < 2; half++) {
      const int k8 = half * 4 + lk;
      const int so = (k8 ^ swz) << 3;
      bf16x8 av[4], bv[4];
#pragma unroll
      for (int m = 0; m < 4; m++)
        av[m] = *(const bf16x8*)&ldsA[(wr * 64 + m * 16 + lr) * 64 + so];
#pragma unroll
      for (int n = 0; n < 4; n++)
        bv[n] = *(const bf16x8*)&ldsB[(wc * 64 + n * 16 + lr) * 64 + so];
#pragma unroll
      for (int m = 0; m < 4; m++)
#pragma unroll
        for (int n = 0; n < 4; n++)
          acc[m][n] = __builtin_amdgcn_mfma_f32_16x16x32_bf16(av[m], bv[n], acc[m][n], 0, 0, 0);
    }
    __syncthreads();
  }

  if (ACT == 2) {
    __shared__ float csum[64];
    if (tid < 64) csum[tid] = 0.f;
    __syncthreads();
#pragma unroll
    for (int n = 0; n < 4; n++) {
      int col = col0 + wc * 64 + n * 16 + lr;
      if (col < N) {
        float bi = bias[col];
        float local = 0.f;
#pragma unroll
        for (int m = 0; m < 4; m++)
#pragma unroll
          for (int g = 0; g < 4; g++) {
            int row = row0 + wr * 64 + m * 16 + lk * 4 + g;
            if (row < M) local += tanhf(acc[m][n][g] + bi);
          }
        atomicAdd(&csum[col], local);
      }
    }
    __syncthreads();
    if (tid < 64) atomicAdd(&Cf[tid], csum[tid]);
    return;
  }

  float su = 0.f;
  if (ACT == 3) su = 1.f / (1.f + expf(-skipp[0]));
  float bi[4];
#pragma unroll
  for (int n = 0; n < 4; n++) {
    int col = col0 + wc * 64 + n * 16 + lr;
    bi[n] = (col < N) ? bias[col] : 0.f;
  }

#pragma unroll
  for (int ch = 0; ch < 2; ch++) {
    __syncthreads();
    if (wr == ch) {
#pragma unroll
      for (int m = 0; m < 4; m++)
#pragma unroll
        for (int n = 0; n < 4; n++)
#pragma unroll
          for (int g = 0; g < 4; g++) {
            int lrow = m * 16 + lk * 4 + g;
            ldsE[lrow * 142 + 17 * (4 * wc + n) + lr] = acc[m][n][g] + bi[n];
          }
    }
    __syncthreads();
#pragma unroll
    for (int i = 0; i < 4; i++) {
      int c = tid + i * 256;            // 0..1023 over 64 rows x 16 col-chunks
      int lrow = c >> 4, cc = c & 15;
      int row = row0 + ch * 64 + lrow;
      int colb = cc * 8;
      float v[8];
#pragma unroll
      for (int q = 0; q < 8; q++)
        v[q] = ldsE[lrow * 142 + 17 * (cc >> 1) + 8 * (cc & 1) + q];
      if (ACT == 1) {
#pragma unroll
        for (int q = 0; q < 8; q++) v[q] = fmaxf(v[q], 0.f);
      }
      if (ACT == 3) {
        u16x8 xp = *(const u16x8*)(xprev + (size_t)row * 256 + col0 + colb);
#pragma unroll
        for (int q = 0; q < 8; q++) v[q] = su * v[q] + (1.f - su) * b2f(xp[q]);
      }
      if (Cb) {
        u16x8 o;
#pragma unroll
        for (int q = 0; q < 8; q++) o[q] = f2b(row < M ? v[q] : 0.f);
        *(u16x8*)(Cb + (size_t)row * ldcb + col0 + colb) = o;
      }
      if (Cf && row < M) {
        int col = col0 + colb;
        if (col < N)
          *(float4*)&Cf[(size_t)row * ldcf + col] = make_float4(v[0], v[1], v[2], v[3]);
        if (col + 4 < N)
          *(float4*)&Cf[(size_t)row * ldcf + col + 4] = make_float4(v[4], v[5], v[6], v[7]);
      }
    }
  }
}

// ============ fused prep: vectorized converts + weight transforms ============
// conv region: 8 elems/thread (two float4 reads -> one u16x8 store)
__global__ __launch_bounds__(256)
void prep_all(const float* __restrict__ x_user, const float* __restrict__ x_drug,
              const float* __restrict__ x_user_ref,
              const float* __restrict__ W_in_user, const float* __restrict__ W_in_drug,
              const float* __restrict__ W_kqv_user, const float* __restrict__ W_kqv_drug,
              const float* __restrict__ W_out_user, const float* __restrict__ W_fin,
              const float* __restrict__ W_han, const float* __restrict__ Wk_sem,
              const float* __restrict__ Wk_uu, const float* __restrict__ Wv_uu,
              const float* __restrict__ Wk_du, const float* __restrict__ Wv_du,
              const float* __restrict__ b_kqv_user, const float* __restrict__ b_kqv_drug,
              unsigned short* __restrict__ xub, unsigned short* __restrict__ xdb,
              unsigned short* __restrict__ xrb,
              unsigned short* __restrict__ Btu_in, unsigned short* __restrict__ Btd_in,
              unsigned short* __restrict__ Btall_u, unsigned short* __restrict__ Btall_d,
              unsigned short* __restrict__ Bto, unsigned short* __restrict__ Btf,
              unsigned short* __restrict__ Bth, unsigned short* __restrict__ BtWk,
              float* __restrict__ ball_u, float* __restrict__ ball_d)
{
  size_t t = (size_t)blockIdx.x * 256 + threadIdx.x;
  // vectorized conv units (8 elems each)
  const size_t u0 = (size_t)NUP * 16;           // xub
  const size_t u1 = u0 + (size_t)NDP * 16;      // xdb
  const size_t u2 = u1 + (size_t)NUP * 16;      // xrb
  // scalar transp units
  const size_t c3 = u2 + 32768;                 // Btu_in (K128,N256)
  const size_t c4 = c3 + 32768;                 // Btd_in
  const size_t c5 = c4 + 65536;                 // Btq -> Btall_u+65536
  const size_t c6 = c5 + 65536;                 // Bto
  const size_t c7 = c6 + 81920;                 // Btf
  const size_t c8 = c7 + 16384;                 // Bth
  const size_t c9 = c8 + 8192;                  // BtWk
  const size_t c10 = c9 + 65536;                // comb ku
  const size_t c11 = c10 + 65536;               // comb vu
  const size_t c12 = c11 + 65536;               // comb kd
  const size_t c13 = c12 + 65536;               // comb vd
  const size_t c14 = c13 + 1280;                // biases
  if (t >= c14) return;

  if (t < u2) {  // vectorized conv_pad x3: unit = 8 contiguous elements
    const float* in; unsigned short* outp; int M; size_t u;
    if (t < u0)      { in = x_user;     outp = xub; M = NU; u = t; }
    else if (t < u1) { in = x_drug;     outp = xdb; M = ND; u = t - u0; }
    else             { in = x_user_ref; outp = xrb; M = NU; u = t - u1; }
    size_t e0 = u * 8;
    int r = (int)(e0 >> 7);
    u16x8 o;
    if (r < M) {
      float4 a = *(const float4*)(in + e0);
      float4 b = *(const float4*)(in + e0 + 4);
      o[0] = f2b(a.x); o[1] = f2b(a.y); o[2] = f2b(a.z); o[3] = f2b(a.w);
      o[4] = f2b(b.x); o[5] = f2b(b.y); o[6] = f2b(b.z); o[7] = f2b(b.w);
    } else {
#pragma unroll
      for (int q = 0; q < 8; q++) o[q] = 0;
    }
    *(u16x8*)(outp + e0) = o;
    return;
  }
  if (t < c9) {  // transp_conv x7 (scalar; small)
    const float* W; unsigned short* Bt; int ldw, coloff, K, N; size_t i;
    if (t < c3)      { W = W_in_user;  Bt = Btu_in;          ldw = 256; coloff = 0;   K = 128; N = 256; i = t - u2; }
    else if (t < c4) { W = W_in_drug;  Bt = Btd_in;          ldw = 256; coloff = 0;   K = 128; N = 256; i = t - c3; }
    else if (t < c5) { W = W_kqv_user; Bt = Btall_u + 65536; ldw = 768; coloff = 256; K = 256; N = 256; i = t - c4; }
    else if (t < c6) { W = W_out_user; Bt = Bto;             ldw = 256; coloff = 0;   K = 256; N = 256; i = t - c5; }
    else if (t < c7) { W = W_fin;      Bt = Btf;             ldw = 256; coloff = 0;   K = 320; N = 256; i = t - c6; }
    else if (t < c8) { W = W_han;      Bt = Bth;             ldw = 64;  coloff = 0;   K = 128; N = 64;  i = t - c7; }
    else             { W = Wk_sem;     Bt = BtWk;            ldw = 64;  coloff = 0;   K = 64;  N = 64;  i = t - c8; }
    int n = (int)(i / K), k = (int)(i - (size_t)n * K);
    Bt[i] = (n < N) ? f2b(W[(size_t)k * ldw + coloff + n]) : 0;
    return;
  }
  if (t < c13) {  // comb_w_t x4
    const float* Wkqv; const float* Wh; unsigned short* Bt; int coloff; size_t i;
    if (t < c10)      { Wkqv = W_kqv_user; Wh = Wk_uu; Bt = Btall_u;          coloff = 0;   i = t - c9; }
    else if (t < c11) { Wkqv = W_kqv_user; Wh = Wv_uu; Bt = Btall_u + 131072; coloff = 512; i = t - c10; }
    else if (t < c12) { Wkqv = W_kqv_drug; Wh = Wk_du; Bt = Btall_d;          coloff = 0;   i = t - c11; }
    else              { Wkqv = W_kqv_drug; Wh = Wv_du; Bt = Btall_d + 65536;  coloff = 512; i = t - c12; }
    int n = (int)(i >> 8), c = (int)(i & 255);
    int hh = n >> 6, e = n & 63;
    float acc = 0.f;
    for (int d = 0; d < 64; d++)
      acc += Wkqv[(size_t)c * 768 + coloff + hh * 64 + d] * Wh[hh * 4096 + d * 64 + e];
    Bt[i] = f2b(acc);
    return;
  }
  { // biases (1280)
    int j = (int)(t - c13);
    const float* b; const float* Wh; float* outp; int coloff, e256;
    if (j < 256)       { outp = &ball_u[j];        b = b_kqv_user; Wh = Wk_uu; coloff = 0;   e256 = j; }
    else if (j < 512)  { ball_u[j] = b_kqv_user[j]; return; }
    else if (j < 768)  { outp = &ball_u[j];        b = b_kqv_user; Wh = Wv_uu; coloff = 512; e256 = j - 512; }
    else if (j < 1024) { outp = &ball_d[j - 768];  b = b_kqv_drug; Wh = Wk_du; coloff = 0;   e256 = j - 768; }
    else               { outp = &ball_d[j - 768];  b = b_kqv_drug; Wh = Wv_du; coloff = 512; e256 = j - 1024; }
    int hh = e256 >> 6, e = e256 & 63;
    float acc = 0.f;
    for (int d = 0; d < 64; d++)
      acc += b[coloff + hh * 64 + d] * Wh[hh * 4096 + d * 64 + e];
    *outp = acc;
  }
}

// ============ CSR build ============
__global__ void hist_all(const int* __restrict__ ei_du, const int* __restrict__ ei_uu,
                         const int* __restrict__ ei_r1, const int* __restrict__ ei_r2,
                         int* __restrict__ cnt)
{
  int t = blockIdx.x * 256 + threadIdx.x;
  if (t >= NEDGE) return;
  const int* ei; int* c;
  switch (blockIdx.y) {
    case 0: ei = ei_du; c = cnt; break;
    case 1: ei = ei_uu; c = cnt; break;
    case 2: ei = ei_r1; c = cnt + NU; break;
    default: ei = ei_r2; c = cnt + 2 * NU; break;
  }
  atomicAdd(&c[ei[NEDGE + t]], 1);
}

__global__ __launch_bounds__(256)
void scan_partial(const int* __restrict__ cnt, int* __restrict__ csums)
{
  int b = blockIdx.x;
  int rel = b / NCH, ch = b - rel * NCH;
  const int* c = cnt + (size_t)rel * NU;
  int t = threadIdx.x;
  int i0 = ch * CHUNK + t * 8;
  int s = 0;
#pragma unroll
  for (int j = 0; j < 8; j++) { int i = i0 + j; if (i < NU) s += c[i]; }
  __shared__ int ps[256];
  ps[t] = s;
  __syncthreads();
  for (int d = 128; d > 0; d >>= 1) { if (t < d) ps[t] += ps[t + d]; __syncthreads(); }
  if (t == 0) csums[b] = ps[0];
}

__global__ void scan_mid(const int* __restrict__ csums, int* __restrict__ coffs,
                         int* __restrict__ rs)
{
  int r = threadIdx.x;
  if (r >= 3) return;
  int run = 0;
  for (int ch = 0; ch < NCH; ch++) { coffs[r * NCH + ch] = run; run += csums[r * NCH + ch]; }
  rs[(size_t)r * NUP + NU] = run;
}

__global__ __launch_bounds__(256)
void scan_final(const int* __restrict__ cnt, const int* __restrict__ coffs,
                int* __restrict__ rs)
{
  int b = blockIdx.x;
  int rel = b / NCH, ch = b - rel * NCH;
  const int* c = cnt + (size_t)rel * NU;
  int* r = rs + (size_t)rel * NUP;
  int t = threadIdx.x;
  int i0 = ch * CHUNK + t * 8;
  int loc[8]; int s = 0;
#pragma unroll
  for (int j = 0; j < 8; j++) { int i = i0 + j; loc[j] = (i < NU) ? c[i] : 0; s += loc[j]; }
  __shared__ int ps[256];
  ps[t] = s;
  __syncthreads();
  for (int d = 1; d < 256; d <<= 1) {
    int o = (t >= d) ? ps[t - d] : 0;
    __syncthreads();
    ps[t] += o;
    __syncthreads();
  }
  int run = coffs[b] + ps[t] - s;
#pragma unroll
  for (int j = 0; j < 8; j++) { int i = i0 + j; if (i < NU) { r[i] = run; run += loc[j]; } }
}

// ============ HAN ============
__global__ void han_alsd(const float* __restrict__ h,
                         const float* __restrict__ a_s1, const float* __restrict__ a_d1,
                         const float* __restrict__ a_s2, const float* __restrict__ a_d2,
                         float* __restrict__ als1, float* __restrict__ ald1,
                         float* __restrict__ als2, float* __restrict__ ald2)
{
  int t = blockIdx.x * 256 + threadIdx.x;
  if (t >= NU * NHEAD) return;
  int n = t >> 2, hh = t & 3;
  const float* hp = h + (size_t)n * 64 + hh * 16;
  float s1 = 0, d1 = 0, s2 = 0, d2 = 0;
#pragma unroll
  for (int d = 0; d < 16; d++) {
    float v = hp[d];
    s1 += v * a_s1[hh * 16 + d]; d1 += v * a_d1[hh * 16 + d];
    s2 += v * a_s2[hh * 16 + d]; d2 += v * a_d2[hh * 16 + d];
  }
  als1[t] = s1; ald1[t] = d1; als2[t] = s2; ald2[t] = d2;
}

// merged: y=0 -> relation 1, y=1 -> relation 2
__global__ void han_fill2(const int* __restrict__ ei1, const int* __restrict__ ei2,
                          const float* __restrict__ als1, const float* __restrict__ ald1,
                          const float* __restrict__ als2, const float* __restrict__ ald2,
                          const int* __restrict__ rs, int* __restrict__ cur,
                          int* __restrict__ esrc1, float* __restrict__ aev1,
                          int* __restrict__ esrc2, float* __restrict__ aev2)
{
  int t = blockIdx.x * 256 + threadIdx.x;
  if (t >= NEDGE * 4) return;
  int y = blockIdx.y;
  const int* ei = y ? ei2 : ei1;
  const float* als = y ? als2 : als1;
  const float* ald = y ? ald2 : ald1;
  const int* rsp = rs + (size_t)(y ? 2 : 1) * NUP;
  int* curp = cur + (size_t)(y ? 2 : 1) * NU;
  int* esrc = y ? esrc2 : esrc1;
  float* aev = y ? aev2 : aev1;
  int e = t >> 2, hh = t & 3;
  int s = ei[e], d = ei[NEDGE + e];
  float al = als[s * 4 + hh] + ald[d * 4 + hh];
  al = (al >= 0.f) ? al : 0.2f * al;
  float ex = expf(al);
  int pos = 0;
  if (hh == 0) pos = rsp[d] + atomicAdd(&curp[d], 1);
  pos = __shfl(pos, (threadIdx.x & 63) & ~3, 64);
  aev[pos * 4 + hh] = ex;
  if (hh == 0) esrc[pos] = s;
}

// merged: one wave per dst row, y selects relation
__global__ __launch_bounds__(256)
void han_gather2(const int* __restrict__ rs,
                 const int* __restrict__ esrc1, const float* __restrict__ aev1,
                 const int* __restrict__ esrc2, const float* __restrict__ aev2,
                 const float* __restrict__ h,
                 unsigned short* __restrict__ obf1, unsigned short* __restrict__ obf2)
{
  int gid = blockIdx.x * 256 + threadIdx.x;
  int wid = gid >> 6, lane = gid & 63;
  if (wid >= NUP) return;
  int y = blockIdx.y;
  const int* rsp = rs + (size_t)(y ? 2 : 1) * NUP;
  const int* esrc = y ? esrc2 : esrc1;
  const float* aev = y ? aev2 : aev1;
  unsigned short* obf = y ? obf2 : obf1;
  int head = lane >> 4;
  int beg = 0, end = 0;
  if (wid < NU) { beg = rsp[wid]; end = rsp[wid + 1]; }
  float asum = 0.f;
  for (int i = beg; i < end; i++) asum += aev[i * 4 + head];
  float inv = 1.f / (asum + 1e-16f);
  float a = 0.f;
  for (int i = beg; i < end; i++)
    a += aev[i * 4 + head] * inv * h[(size_t)esrc[i] * 64 + lane];
  obf[(size_t)wid * 64 + lane] = f2b(fmaxf(a, 0.f));
}

__global__ void sem_final2(const float* __restrict__ colpart2,
                           const float* __restrict__ q_sem, float* __restrict__ semv)
{
  int t = threadIdx.x;            // 128
  int j = t & 63;
  __shared__ float sv[128];
  sv[t] = colpart2[t] * q_sem[j] * (1.0f / NU);
  __syncthreads();
  if (t == 0) {
    float s0 = 0, s1 = 0;
    for (int i = 0; i < 64; i++) { s0 += sv[i]; s1 += sv[64 + i]; }
    float m = fmaxf(s0, s1);
    float e0 = expf(s0 - m), e1 = expf(s1 - m);
    semv[0] = e0 / (e0 + e1); semv[1] = e1 / (e0 + e1);
  }
}

// ============ HGT ============
// merged: y=0 -> du edges (k from kvdb), y=1 -> uu edges (k from qukvb)
__global__ void hgt_fill2(const int* __restrict__ ei_du, const int* __restrict__ ei_uu,
                          const unsigned short* __restrict__ qb,
                          const unsigned short* __restrict__ kvdb,
                          const float* __restrict__ p_du, const float* __restrict__ p_uu,
                          const int* __restrict__ rs, int* __restrict__ cur,
                          int* __restrict__ esrc, float* __restrict__ aev)
{
  int t = blockIdx.x * 256 + threadIdx.x;
  if (t >= NEDGE * 4) return;
  int y = blockIdx.y;
  const int* ei = y ? ei_uu : ei_du;
  const unsigned short* kb = y ? qb : kvdb;
  const int ks = y ? 768 : 512;
  const int voff = y ? 512 : NUP * 768 + 256;
  const float* p = y ? p_uu : p_du;
  int e = t >> 2, hh = t & 3;
  int s = ei[e], d = ei[NEDGE + e];
  const uint4* qv = (const uint4*)(qb + (size_t)d * 768 + 256 + hh * 64);
  const uint4* kv = (const uint4*)(kb + (size_t)s * ks + hh * 64);
  float acc = 0.f;
#pragma unroll
  for (int i = 0; i < 8; i++) {
    uint4 a = qv[i], b = kv[i];
    unsigned int aw[4] = {a.x, a.y, a.z, a.w};
    unsigned int bw[4] = {b.x, b.y, b.z, b.w};
#pragma unroll
    for (int u = 0; u < 4; u++) {
      acc += b2f((unsigned short)(aw[u] & 0xffff)) * b2f((unsigned short)(bw[u] & 0xffff));
      acc += b2f((unsigned short)(aw[u] >> 16))    * b2f((unsigned short)(bw[u] >> 16));
    }
  }
  float ex = expf(acc * p[hh] * 0.125f);
  int pos = 0;
  if (hh == 0) pos = rs[d] + atomicAdd(&cur[d], 1);
  pos = __shfl(pos, (threadIdx.x & 63) & ~3, 64);
  aev[pos * 4 + hh] = ex;
  if (hh == 0) esrc[pos] = voff + s * ks;
}

__global__ __launch_bounds__(256)
void hgt_gather(const int* __restrict__ rs, const int* __restrict__ esrc,
                const float* __restrict__ aev, const unsigned short* __restrict__ vbase,
                unsigned short* __restrict__ houtb)
{
  int gid = blockIdx.x * 256 + threadIdx.x;
  int wid = gid >> 6, lane = gid & 63;
  if (wid >= NUP) return;
  int head = lane >> 4;
  int beg = 0, end = 0;
  if (wid < NU) { beg = rs[wid]; end = rs[wid + 1]; }
  float asum = 0.f;
  for (int i = beg; i < end; i++) asum += aev[i * 4 + head];
  float inv = 1.f / (asum + 1e-16f);
  float a0 = 0, a1 = 0, a2 = 0, a3 = 0;
  for (int i = beg; i < end; i++) {
    float w = aev[i * 4 + head] * inv;
    const ushort4 v = *(const ushort4*)(vbase + (size_t)esrc[i] + lane * 4);
    a0 += b2f(v.x) * w; a1 += b2f(v.y) * w; a2 += b2f(v.z) * w; a3 += b2f(v.w) * w;
  }
  ushort4 o;
  o.x = f2b(0.5f * a0 * (1.f + erff(a0 * 0.70710678118654752f)));
  o.y = f2b(0.5f * a1 * (1.f + erff(a1 * 0.70710678118654752f)));
  o.z = f2b(0.5f * a2 * (1.f + erff(a2 * 0.70710678118654752f)));
  o.w = f2b(0.5f * a3 * (1.f + erff(a3 * 0.70710678118654752f)));
  *(ushort4*)(houtb + (size_t)wid * 256 + lane * 4) = o;
}

// ============ epilogues ============
// covers ALL NUP rows (zero for pad) -> no separate memset needed
__global__ void fill_ref_b(const unsigned short* __restrict__ obf1,
                           const unsigned short* __restrict__ obf2,
                           const float* __restrict__ semv, unsigned short* __restrict__ afinb)
{
  int t = blockIdx.x * 256 + threadIdx.x;  // n*64 + j
  if (t >= NUP * 64) return;
  int n = t >> 6, j = t & 63;
  float v = semv[0] * b2f(obf1[t]) + semv[1] * b2f(obf2[t]);  // pad rows are 0
  afinb[(size_t)n * 320 + 256 + j] = f2b(v);
}

// ------------------------------------------------------------------
extern "C" void kernel_launch(void* const* d_in, const int* in_sizes, int n_in,
                              void* d_out, int out_size, void* d_ws, size_t ws_size,
                              hipStream_t stream)
{
  (void)in_sizes; (void)n_in; (void)out_size; (void)ws_size;
  const float* x_user     = (const float*)d_in[0];
  const float* x_drug     = (const float*)d_in[1];
  const float* x_user_ref = (const float*)d_in[2];
  const int*   ei_du      = (const int*)d_in[4];
  const int*   ei_uu      = (const int*)d_in[5];
  const int*   ei_r1      = (const int*)d_in[6];
  const int*   ei_r2      = (const int*)d_in[7];
  const float* W_han      = (const float*)d_in[8];
  const float* b_han      = (const float*)d_in[9];
  const float* a_src_r1   = (const float*)d_in[10];
  const float* a_dst_r1   = (const float*)d_in[11];
  const float* a_src_r2   = (const float*)d_in[12];
  const float* a_dst_r2   = (const float*)d_in[13];
  const float* Wk_sem     = (const float*)d_in[14];
  const float* bk_sem     = (const float*)d_in[15];
  const float* q_sem      = (const float*)d_in[16];
  const float* W_in_user  = (const float*)d_in[17];
  const float* b_in_user  = (const float*)d_in[18];
  const float* W_in_drug  = (const float*)d_in[19];
  const float* b_in_drug  = (const float*)d_in[20];
  const float* W_kqv_user = (const float*)d_in[21];
  const float* b_kqv_user = (const float*)d_in[22];
  const float* W_kqv_drug = (const float*)d_in[23];
  const float* b_kqv_drug = (const float*)d_in[24];
  const float* Wk_du      = (const float*)d_in[28];
  const float* Wv_du      = (const float*)d_in[29];
  const float* p_du       = (const float*)d_in[30];
  const float* Wk_uu      = (const float*)d_in[31];
  const float* Wv_uu      = (const float*)d_in[32];
  const float* p_uu       = (const float*)d_in[33];
  const float* W_out_user = (const float*)d_in[34];
  const float* b_out_user = (const float*)d_in[35];
  const float* skip_user  = (const float*)d_in[38];
  const float* W_fin      = (const float*)d_in[40];
  const float* b_fin      = (const float*)d_in[41];
  float* out = (float*)d_out;

  // ---------------- workspace ----------------
  char* base = (char*)d_ws;
  size_t off = 0;
  auto alloc = [&](size_t bytes) { char* p = base + off; off += (bytes + 255) & ~(size_t)255; return p; };

  float* h       = (float*)alloc((size_t)NU * 64 * 4);
  float* als1    = (float*)alloc((size_t)NU * 4 * 4);
  float* ald1    = (float*)alloc((size_t)NU * 4 * 4);
  float* als2    = (float*)alloc((size_t)NU * 4 * 4);
  float* ald2    = (float*)alloc((size_t)NU * 4 * 4);
  float* colpart2= (float*)alloc(128 * 4);
  float* semv    = (float*)alloc(64);
  float* ball_u  = (float*)alloc(768 * 4);
  float* ball_d  = (float*)alloc(512 * 4);

  int* cnt   = (int*)alloc((size_t)3 * NU * 4);
  int* rs    = (int*)alloc((size_t)3 * NUP * 4);
  int* csums = (int*)alloc((size_t)3 * NCH * 4);
  int* coffs = (int*)alloc((size_t)3 * NCH * 4);
  int* esrcH = (int*)alloc((size_t)2 * NEDGE * 4);
  float* aevH= (float*)alloc((size_t)2 * NEDGE * 4 * 4);
  int* esrc1 = (int*)alloc((size_t)NEDGE * 4);
  float* aev1= (float*)alloc((size_t)NEDGE * 4 * 4);
  int* esrc2 = (int*)alloc((size_t)NEDGE * 4);
  float* aev2= (float*)alloc((size_t)NEDGE * 4 * 4);

  unsigned short* obf1 = (unsigned short*)alloc((size_t)NUP * 64 * 2);
  unsigned short* obf2 = (unsigned short*)alloc((size_t)NUP * 64 * 2);

  unsigned short* qukvb = (unsigned short*)alloc((size_t)NUP * 768 * 2);
  unsigned short* kvdb  = (unsigned short*)alloc((size_t)NDP * 512 * 2);

  unsigned short* xub2d = (unsigned short*)alloc((size_t)NUP * 256 * 2);
  unsigned short* xdb2d = (unsigned short*)alloc((size_t)NDP * 256 * 2);

  unsigned short* houtb = (unsigned short*)alloc((size_t)NUP * 256 * 2);
  unsigned short* xrb   = houtb;

  unsigned short* afinb = (unsigned short*)alloc((size_t)NUP * 320 * 2);
  unsigned short* xub   = afinb;
  unsigned short* xdb   = afinb + (size_t)NUP * 128;

  unsigned short* Btu_in  = (unsigned short*)alloc(256 * 128 * 2);
  unsigned short* Btd_in  = (unsigned short*)alloc(256 * 128 * 2);
  unsigned short* Btall_u = (unsigned short*)alloc(768 * 256 * 2);
  unsigned short* Btall_d = (unsigned short*)alloc(512 * 256 * 2);
  unsigned short* Bto     = (unsigned short*)alloc(256 * 256 * 2);
  unsigned short* Btf     = (unsigned short*)alloc(256 * 320 * 2);
  unsigned short* Bth     = (unsigned short*)alloc(128 * 128 * 2);
  unsigned short* BtWk    = (unsigned short*)alloc(128 * 64 * 2);

  const int B = 256;
  dim3 blk(B);
  auto g1 = [](size_t n) { return dim3((unsigned)((n + 255) / 256)); };
  auto gg = [](int N, int Mblk) {
    int Nx = (N + 127) / 128;
    return dim3((unsigned)(((Mblk + 7) / 8) * 8 * Nx));
  };

  // ===== fused prep (conv region vectorized x8) =====
  const size_t prep_total = (size_t)NUP * 16 * 2 + (size_t)NDP * 16
                          + 32768 * 2 + 65536 * 2 + 81920 + 16384 + 8192
                          + 65536 * 4 + 1280;
  prep_all<<<g1(prep_total), blk, 0, stream>>>(
      x_user, x_drug, x_user_ref, W_in_user, W_in_drug, W_kqv_user, W_kqv_drug,
      W_out_user, W_fin, W_han, Wk_sem, Wk_uu, Wv_uu, Wk_du, Wv_du,
      b_kqv_user, b_kqv_drug,
      xub, xdb, xrb, Btu_in, Btd_in, Btall_u, Btall_d, Bto, Btf, Bth, BtWk,
      ball_u, ball_d);

  // ===== CSR build =====
  hipMemsetAsync(cnt, 0, (size_t)3 * NU * 4, stream);
  hist_all<<<dim3((NEDGE + 255) / 256, 4), blk, 0, stream>>>(ei_du, ei_uu, ei_r1, ei_r2, cnt);
  scan_partial<<<3 * NCH, blk, 0, stream>>>(cnt, csums);
  scan_mid<<<1, 64, 0, stream>>>(csums, coffs, rs);
  scan_final<<<3 * NCH, blk, 0, stream>>>(cnt, coffs, rs);
  hipMemsetAsync(cnt, 0, (size_t)3 * NU * 4, stream);
  hipMemsetAsync(colpart2, 0, 128 * 4, stream);

  // ===== HAN branch =====
  gemm_bf16<0><<<gg(64, 313), blk, 0, stream>>>(
      xrb, Bth, b_han, h, 64, (unsigned short*)nullptr, 0, NU, 64, 128, 313, nullptr, nullptr);

  han_alsd<<<g1((size_t)NU * 4), blk, 0, stream>>>(
      h, a_src_r1, a_dst_r1, a_src_r2, a_dst_r2, als1, ald1, als2, ald2);

  han_fill2<<<dim3((NEDGE * 4 + 255) / 256, 2), blk, 0, stream>>>(
      ei_r1, ei_r2, als1, ald1, als2, ald2, rs, cnt, esrc1, aev1, esrc2, aev2);
  han_gather2<<<dim3((NUP * 64 + 255) / 256, 2), blk, 0, stream>>>(
      rs, esrc1, aev1, esrc2, aev2, h, obf1, obf2);

  gemm_bf16<2><<<gg(64, 313), blk, 0, stream>>>(
      obf1, BtWk, bk_sem, colpart2, 0, (unsigned short*)nullptr, 0, NU, 64, 64, 313, nullptr, nullptr);
  gemm_bf16<2><<<gg(64, 313), blk, 0, stream>>>(
      obf2, BtWk, bk_sem, colpart2 + 64, 0, (unsigned short*)nullptr, 0, NU, 64, 64, 313, nullptr, nullptr);
  sem_final2<<<1, 128, 0, stream>>>(colpart2, q_sem, semv);

  // ===== HGT GEMMs =====
  gemm_bf16<1><<<gg(256, 313), blk, 0, stream>>>(
      xub, Btu_in, b_in_user, (float*)nullptr, 0, xub2d, 256, NU, 256, 128, 313, nullptr, nullptr);
  gemm_bf16<1><<<gg(256, 157), blk, 0, stream>>>(
      xdb, Btd_in, b_in_drug, (float*)nullptr, 0, xdb2d, 256, ND, 256, 128, 157, nullptr, nullptr);

  gemm_bf16<0><<<gg(768, 313), blk, 0, stream>>>(
      xub2d, Btall_u, ball_u, (float*)nullptr, 0, qukvb, 768, NU, 768, 256, 313, nullptr, nullptr);
  gemm_bf16<0><<<gg(512, 157), blk, 0, stream>>>(
      xdb2d, Btall_d, ball_d, (float*)nullptr, 0, kvdb, 512, ND, 512, 256, 157, nullptr, nullptr);

  // ===== HGT attention =====
  hgt_fill2<<<dim3((NEDGE * 4 + 255) / 256, 2), blk, 0, stream>>>(
      ei_du, ei_uu, qukvb, kvdb, p_du, p_uu, rs, cnt, esrcH, aevH);
  hgt_gather<<<g1((size_t)NUP * 64), blk, 0, stream>>>(rs, esrcH, aevH, qukvb, houtb);

  // ===== output head =====
  gemm_bf16<3><<<gg(256, 313), blk, 0, stream>>>(
      houtb, Bto, b_out_user, (float*)nullptr, 0, afinb, 320, NU, 256, 256, 313, skip_user, xub2d);
  fill_ref_b<<<g1((size_t)NUP * 64), blk, 0, stream>>>(obf1, obf2, semv, afinb);

  gemm_bf16<0><<<gg(256, 313), blk, 0, stream>>>(
      afinb, Btf, b_fin, out, 256, (unsigned short*)nullptr, 0, NU, 256, 320, 313, nullptr, nullptr);
}